// Round 10
// baseline (94.348 us; speedup 1.0000x reference)
//
#include <hip/hip_runtime.h>
#include <hip/hip_bf16.h>
#include <stdint.h>

typedef unsigned long long u64;

#define S 16            // slices per row
#define NB 8192         // histogram bins = top 13 bits of monotone float key
#define KSHIFT 19       // 32-13
#define CAND_MAX 4096   // per-row candidate capacity (LDS)
#define NT1 256
#define NTF 1024
#define NWF (NTF / 64)
#define ITER1 8         // register-staged float4s per thread in pass1

__device__ __forceinline__ unsigned fkey(float x) {
    unsigned u = __float_as_uint(x);
    return ((int)u < 0) ? ~u : (u | 0x80000000u);
}

// ---------------- K0: fast workspace zero ----------------
__global__ __launch_bounds__(256) void k_zero(uint4* __restrict__ p, int n16)
{
    const uint4 z = make_uint4(0u, 0u, 0u, 0u);
    for (int i = blockIdx.x * 256 + threadIdx.x; i < n16; i += gridDim.x * 256)
        p[i] = z;
}

// ---------------- K1: single sweep: slice max + exp-sum(slice max) + histogram ----
__global__ __launch_bounds__(NT1) void k_pass1(
    const float* __restrict__ logits, const float* __restrict__ temps,
    float* __restrict__ gmax, float* __restrict__ gsum,
    unsigned* __restrict__ ghist, int V, int slen)
{
    const int s = blockIdx.x, b = blockIdx.y, tid = threadIdx.x;
    __shared__ unsigned h[NB];
    __shared__ float red[NT1 / 64];
    __shared__ float s_ms;
    for (int i = tid; i < NB; i += NT1) h[i] = 0u;

    const float t = temps[b];
    const float* xrow = logits + (size_t)b * (size_t)V;
    const int beg = s * slen, end = min(V, beg + slen);
    const float4* x4 = (const float4*)xrow;
    const int beg4 = beg >> 2, end4 = end >> 2;
    const int reg_end = beg4 + ITER1 * NT1;

    float4 r[ITER1];
    #pragma unroll
    for (int k = 0; k < ITER1; ++k) {
        int idx = beg4 + k * NT1 + tid;
        r[k] = (idx < end4) ? x4[idx] : make_float4(-INFINITY, -INFINITY, -INFINITY, -INFINITY);
    }

    float lmax = -INFINITY;
    #pragma unroll
    for (int k = 0; k < ITER1; ++k)
        lmax = fmaxf(lmax, fmaxf(fmaxf(r[k].x, r[k].y), fmaxf(r[k].z, r[k].w)));
    for (int idx = reg_end + tid; idx < end4; idx += NT1) {
        float4 v = x4[idx];
        lmax = fmaxf(lmax, fmaxf(fmaxf(v.x, v.y), fmaxf(v.z, v.w)));
    }
    for (int i = max(beg, end4 << 2) + tid; i < end; i += NT1)
        lmax = fmaxf(lmax, xrow[i]);
    for (int off = 32; off > 0; off >>= 1) lmax = fmaxf(lmax, __shfl_xor(lmax, off));
    if ((tid & 63) == 0) red[tid >> 6] = lmax;
    __syncthreads();
    if (tid == 0) {
        float m = red[0];
        for (int w = 1; w < NT1 / 64; ++w) m = fmaxf(m, red[w]);
        gmax[b * S + s] = m;
        s_ms = m / t;
    }
    __syncthreads();
    const float ms = s_ms;

    float lsum = 0.f;
    #pragma unroll
    for (int k = 0; k < ITER1; ++k) {
        int idx = beg4 + k * NT1 + tid;
        if (idx < end4) {
            float e0 = expf(r[k].x / t - ms), e1 = expf(r[k].y / t - ms);
            float e2 = expf(r[k].z / t - ms), e3 = expf(r[k].w / t - ms);
            lsum += e0; lsum += e1; lsum += e2; lsum += e3;
            atomicAdd(&h[fkey(r[k].x) >> KSHIFT], 1u);
            atomicAdd(&h[fkey(r[k].y) >> KSHIFT], 1u);
            atomicAdd(&h[fkey(r[k].z) >> KSHIFT], 1u);
            atomicAdd(&h[fkey(r[k].w) >> KSHIFT], 1u);
        }
    }
    for (int idx = reg_end + tid; idx < end4; idx += NT1) {
        float4 v = x4[idx];
        float e0 = expf(v.x / t - ms), e1 = expf(v.y / t - ms);
        float e2 = expf(v.z / t - ms), e3 = expf(v.w / t - ms);
        lsum += e0; lsum += e1; lsum += e2; lsum += e3;
        atomicAdd(&h[fkey(v.x) >> KSHIFT], 1u);
        atomicAdd(&h[fkey(v.y) >> KSHIFT], 1u);
        atomicAdd(&h[fkey(v.z) >> KSHIFT], 1u);
        atomicAdd(&h[fkey(v.w) >> KSHIFT], 1u);
    }
    for (int i = max(beg, end4 << 2) + tid; i < end; i += NT1) {
        float x = xrow[i];
        float e = expf(x / t - ms);
        lsum += e;
        atomicAdd(&h[fkey(x) >> KSHIFT], 1u);
    }
    for (int off = 32; off > 0; off >>= 1) lsum += __shfl_xor(lsum, off);
    if ((tid & 63) == 0) red[tid >> 6] = lsum;
    __syncthreads();
    if (tid == 0) {
        float sum = 0.f;
        for (int w = 0; w < NT1 / 64; ++w) sum += red[w];
        gsum[b * S + s] = sum;
    }
    unsigned* gh = ghist + (size_t)b * NB;
    for (int i = tid; i < NB; i += NT1)
        if (h[i]) atomicAdd(&gh[i], h[i]);
}

// ---------------- K2: per-row: thr+m+denom, filter row -> LDS, exp, sort, sample ----
__global__ __launch_bounds__(NTF) void k_finish2(
    const float* __restrict__ logits, const unsigned* __restrict__ ghist,
    const float* __restrict__ gmax, const float* __restrict__ gsum,
    const float* __restrict__ temps, const float* __restrict__ minps,
    const float* __restrict__ topps, const int* __restrict__ topks,
    const float* __restrict__ us, int* __restrict__ out, int V)
{
    const int b = blockIdx.x, tid = threadIdx.x;
    __shared__ u64 cand[CAND_MAX];
    __shared__ float wsum[NWF];
    __shared__ unsigned wfirst[NWF];
    __shared__ float s_m, s_den;
    __shared__ unsigned s_thr, s_cnt;
    if (tid == 0) s_cnt = 0u;

    const float t = temps[b];

    // ---- wave 0: row max, denom, topk-tight threshold (margin 0; bin-atomic ties) ----
    if (tid < 64) {
        const int lane = tid;
        float v = (lane < S) ? gmax[b * S + lane] : -INFINITY;
        float vv = v;
        for (int off = 32; off > 0; off >>= 1) vv = fmaxf(vv, __shfl_xor(vv, off));
        const float m = vv / t;
        float d = (lane < S) ? gsum[b * S + lane] * expf(v / t - m) : 0.f;
        for (int off = 32; off > 0; off >>= 1) d += __shfl_xor(d, off);

        const unsigned needed = (unsigned)topks[b];
        const unsigned* h = ghist + (size_t)b * NB;
        const int CH = NB / 64;
        const int base = lane * CH;
        unsigned c = 0;
        for (int j = 0; j < CH; ++j) c += h[base + j];
        unsigned tsuf = c;
        for (int off = 1; off < 64; off <<= 1) {
            unsigned o = __shfl_down(tsuf, off);
            if (lane + off < 64) tsuf += o;
        }
        u64 mask = __ballot(tsuf >= needed);
        int lstar = 63 - __builtin_clzll(mask);
        unsigned above = __shfl(tsuf, (lstar + 1) & 63);
        if (lstar == 63) above = 0u;
        if (lane == 0) {
            unsigned run = above;
            int thrbin = lstar * CH;
            for (int bb = lstar * CH + CH - 1; bb >= lstar * CH; --bb) {
                run += h[bb];
                if (run >= needed) { thrbin = bb; break; }
            }
            s_thr = (unsigned)thrbin << KSHIFT;
            s_m = m;
            s_den = d;
        }
    }
    __syncthreads();
    const unsigned thr = s_thr;
    const float m = s_m, denom = s_den;

    // ---- filter row into LDS (block-local atomics only) ----
    const float* xrow = logits + (size_t)b * (size_t)V;
    const float4* x4 = (const float4*)xrow;
    const int n4 = V >> 2;
    for (int i = tid; i < n4; i += NTF) {
        float4 v = x4[i];
        const int i0 = i << 2;
        if (fkey(v.x) >= thr) { unsigned p = atomicAdd(&s_cnt, 1u); if (p < CAND_MAX) cand[p] = ((u64)__float_as_uint(v.x) << 32) | (unsigned)(i0    ); }
        if (fkey(v.y) >= thr) { unsigned p = atomicAdd(&s_cnt, 1u); if (p < CAND_MAX) cand[p] = ((u64)__float_as_uint(v.y) << 32) | (unsigned)(i0 + 1); }
        if (fkey(v.z) >= thr) { unsigned p = atomicAdd(&s_cnt, 1u); if (p < CAND_MAX) cand[p] = ((u64)__float_as_uint(v.z) << 32) | (unsigned)(i0 + 2); }
        if (fkey(v.w) >= thr) { unsigned p = atomicAdd(&s_cnt, 1u); if (p < CAND_MAX) cand[p] = ((u64)__float_as_uint(v.w) << 32) | (unsigned)(i0 + 3); }
    }
    for (int i = (n4 << 2) + tid; i < V; i += NTF) {
        float x = xrow[i];
        if (fkey(x) >= thr) { unsigned p = atomicAdd(&s_cnt, 1u); if (p < CAND_MAX) cand[p] = ((u64)__float_as_uint(x) << 32) | (unsigned)i; }
    }
    __syncthreads();
    int n = (int)min(s_cnt, (unsigned)CAND_MAX);

    // ---- exp + repack in place: (x_bits, idx) -> (p_bits, ~idx) ----
    for (int i = tid; i < n; i += NTF) {
        u64 w = cand[i];
        float x = __uint_as_float((unsigned)(w >> 32));
        float e = expf(x / t - m);
        float p = e / denom;
        cand[i] = ((u64)__float_as_uint(p) << 32) | (unsigned)(~(unsigned)w);
    }
    int n2 = 1; while (n2 < n) n2 <<= 1;
    for (int i = n + tid; i < n2; i += NTF) cand[i] = 0ULL;
    __syncthreads();

    // ---- bitonic sort, descending by (p_bits, ~idx) ----
    for (int k = 2; k <= n2; k <<= 1) {
        for (int j = k >> 1; j > 0; j >>= 1) {
            for (int i = tid; i < n2; i += NTF) {
                int ixj = i ^ j;
                if (ixj > i) {
                    u64 a = cand[i], bb = cand[ixj];
                    bool sw = ((i & k) == 0) ? (a < bb) : (a > bb);
                    if (sw) { cand[i] = bb; cand[ixj] = a; }
                }
            }
            __syncthreads();
        }
    }

    // ---- parallel epilogue: thread i owns sorted element i ----
    const int lane = tid & 63, wv = tid >> 6;
    const float topp = topps[b], minp = minps[b], uu = us[b];
    int tk = topks[b];
    if (tk > n) tk = n;
    if (tk > NTF) tk = NTF;

    float p = 0.f;
    if (tid < tk) p = __uint_as_float((unsigned)(cand[tid] >> 32));

    float c = p;
    #pragma unroll
    for (int off = 1; off < 64; off <<= 1) {
        float o = __shfl_up(c, off);
        if (lane >= off) c += o;
    }
    if (lane == 63) wsum[wv] = c;
    __syncthreads();
    if (tid < 64) {
        float sv = (tid < NWF) ? wsum[tid] : 0.f;
        #pragma unroll
        for (int off = 1; off < NWF; off <<= 1) {
            float o = __shfl_up(sv, off);
            if (tid >= off) sv += o;
        }
        if (tid < NWF) wsum[tid] = sv;
    }
    __syncthreads();
    float cum = c + ((wv > 0) ? wsum[wv - 1] : 0.f);
    float excl = cum - p;                       // replicate (cumsum - p) rounding shape
    float p0 = __uint_as_float((unsigned)(cand[0] >> 32));
    float thrmp = p0 * minp;
    float p1v = (excl <= topp) ? p : 0.f;
    float v = (p1v >= thrmp) ? p1v : 0.f;
    __syncthreads();

    float cv = v;
    #pragma unroll
    for (int off = 1; off < 64; off <<= 1) {
        float o = __shfl_up(cv, off);
        if (lane >= off) cv += o;
    }
    if (lane == 63) wsum[wv] = cv;
    __syncthreads();
    if (tid < 64) {
        float sv = (tid < NWF) ? wsum[tid] : 0.f;
        #pragma unroll
        for (int off = 1; off < NWF; off <<= 1) {
            float o = __shfl_up(sv, off);
            if (tid >= off) sv += o;
        }
        if (tid < NWF) wsum[tid] = sv;
    }
    __syncthreads();
    float cdf = cv + ((wv > 0) ? wsum[wv - 1] : 0.f);
    float total = wsum[NWF - 1];
    float target = uu * total;

    bool hit = (tid < tk) && (cdf > target);
    u64 mk = __ballot(hit);
    if (lane == 0) wfirst[wv] = mk ? (unsigned)__builtin_ctzll(mk) : 0xFFFFFFFFu;
    __syncthreads();
    if (tid == 0) {
        int sel = -1;
        for (int w = 0; w < NWF; ++w)
            if (wfirst[w] != 0xFFFFFFFFu) { sel = w * 64 + (int)wfirst[w]; break; }
        if (sel < 0) sel = 0;
        out[b] = (int)~(unsigned)cand[sel];
    }
}

// ---------------- Fallback: monolithic single kernel (round-1, passed) ----------------
#define FNT 512
#define FNBINS 1024
#define FKMARGIN 1224
__global__ __launch_bounds__(FNT) void sampler_mono(
    const float* __restrict__ logits, const float* __restrict__ temps,
    const float* __restrict__ minps, const float* __restrict__ topps,
    const int* __restrict__ topks, const float* __restrict__ us,
    int* __restrict__ out, int V)
{
    const int row = blockIdx.x;
    const int tid = threadIdx.x;
    const float t = temps[row];
    __shared__ unsigned int hist[FNBINS];
    __shared__ u64 cand[CAND_MAX];
    __shared__ float red[FNT / 64];
    __shared__ float s_m, s_denom;
    __shared__ unsigned s_thr, s_cnt;
    for (int i = tid; i < FNBINS; i += FNT) hist[i] = 0u;
    if (tid == 0) s_cnt = 0u;
    const float* xrow = logits + (size_t)row * (size_t)V;
    const int n4 = V >> 2;
    const float4* x4 = (const float4*)xrow;
    float lmax = -INFINITY;
    for (int i = tid; i < n4; i += FNT) {
        float4 v = x4[i];
        lmax = fmaxf(lmax, fmaxf(fmaxf(v.x, v.y), fmaxf(v.z, v.w)));
    }
    for (int i = (n4 << 2) + tid; i < V; i += FNT) lmax = fmaxf(lmax, xrow[i]);
    for (int off = 32; off > 0; off >>= 1) lmax = fmaxf(lmax, __shfl_xor(lmax, off));
    if ((tid & 63) == 0) red[tid >> 6] = lmax;
    __syncthreads();
    if (tid == 0) {
        float r = red[0];
        for (int w = 1; w < FNT / 64; ++w) r = fmaxf(r, red[w]);
        s_m = r / t;
    }
    __syncthreads();
    const float m = s_m;
    float lsum = 0.f;
    for (int i = tid; i < n4; i += FNT) {
        float4 v = x4[i];
        float e0 = expf(v.x / t - m), e1 = expf(v.y / t - m);
        float e2 = expf(v.z / t - m), e3 = expf(v.w / t - m);
        lsum += e0; lsum += e1; lsum += e2; lsum += e3;
        atomicAdd(&hist[__float_as_uint(e0) >> 20], 1u);
        atomicAdd(&hist[__float_as_uint(e1) >> 20], 1u);
        atomicAdd(&hist[__float_as_uint(e2) >> 20], 1u);
        atomicAdd(&hist[__float_as_uint(e3) >> 20], 1u);
    }
    for (int i = (n4 << 2) + tid; i < V; i += FNT) {
        float e = expf(xrow[i] / t - m);
        lsum += e;
        atomicAdd(&hist[__float_as_uint(e) >> 20], 1u);
    }
    for (int off = 32; off > 0; off >>= 1) lsum += __shfl_xor(lsum, off);
    if ((tid & 63) == 0) red[tid >> 6] = lsum;
    __syncthreads();
    if (tid == 0) {
        float r = 0.f;
        for (int w = 0; w < FNT / 64; ++w) r += red[w];
        s_denom = r;
    }
    __syncthreads();
    const float denom = s_denom;
    if (tid < 64) {
        const int lane = tid;
        const int CH = FNBINS / 64;
        const int base = lane * CH;
        unsigned c = 0;
        #pragma unroll
        for (int j = 0; j < CH; ++j) c += hist[base + j];
        unsigned tsuf = c;
        #pragma unroll
        for (int off = 1; off < 64; off <<= 1) {
            unsigned o = __shfl_down(tsuf, off);
            if (lane + off < 64) tsuf += o;
        }
        unsigned long long mask = __ballot(tsuf >= (unsigned)FKMARGIN);
        int lstar = 63 - __builtin_clzll(mask);
        unsigned above = __shfl(tsuf, (lstar + 1) & 63);
        if (lstar == 63) above = 0u;
        if (lane == 0) {
            unsigned run = above;
            int thrbin = lstar * CH;
            for (int bb = lstar * CH + CH - 1; bb >= lstar * CH; --bb) {
                run += hist[bb];
                if (run >= (unsigned)FKMARGIN) { thrbin = bb; break; }
            }
            s_thr = (unsigned)thrbin << 20;
        }
    }
    __syncthreads();
    const unsigned thrkey = s_thr;
    for (int i = tid; i < n4; i += FNT) {
        float4 v = x4[i];
        float e[4] = { expf(v.x / t - m), expf(v.y / t - m),
                       expf(v.z / t - m), expf(v.w / t - m) };
        #pragma unroll
        for (int c = 0; c < 4; ++c) {
            unsigned eb = __float_as_uint(e[c]);
            if (eb >= thrkey) {
                float p = e[c] / denom;
                unsigned pos = atomicAdd(&s_cnt, 1u);
                if (pos < CAND_MAX)
                    cand[pos] = ((u64)__float_as_uint(p) << 32) | (unsigned)(~(unsigned)((i << 2) + c));
            }
        }
    }
    for (int i = (n4 << 2) + tid; i < V; i += FNT) {
        float e = expf(xrow[i] / t - m);
        if (__float_as_uint(e) >= thrkey) {
            float p = e / denom;
            unsigned pos = atomicAdd(&s_cnt, 1u);
            if (pos < CAND_MAX)
                cand[pos] = ((u64)__float_as_uint(p) << 32) | (unsigned)(~(unsigned)i);
        }
    }
    __syncthreads();
    int n = (int)s_cnt; if (n > CAND_MAX) n = CAND_MAX;
    int n2 = 1; while (n2 < n) n2 <<= 1;
    for (int i = n + tid; i < n2; i += FNT) cand[i] = 0ULL;
    __syncthreads();
    for (int k = 2; k <= n2; k <<= 1) {
        for (int j = k >> 1; j > 0; j >>= 1) {
            for (int i = tid; i < n2; i += FNT) {
                int ixj = i ^ j;
                if (ixj > i) {
                    u64 a = cand[i], bb = cand[ixj];
                    bool sw = ((i & k) == 0) ? (a < bb) : (a > bb);
                    if (sw) { cand[i] = bb; cand[ixj] = a; }
                }
            }
            __syncthreads();
        }
    }
    if (tid == 0) {
        const float topp = topps[row], minp = minps[row], uu = us[row];
        int tk = topks[row];
        if (tk > n) tk = n;
        float p0 = __uint_as_float((unsigned)(cand[0] >> 32));
        float thrmp = p0 * minp;
        float cum = 0.f, total = 0.f;
        for (int i = 0; i < tk; ++i) {
            float p = __uint_as_float((unsigned)(cand[i] >> 32));
            cum = cum + p;
            float excl = cum - p;
            float p1 = (excl <= topp) ? p : 0.f;
            float v = (p1 >= thrmp) ? p1 : 0.f;
            total += v;
        }
        float target = uu * total;
        float cdf = 0.f; int sel = -1;
        cum = 0.f;
        for (int i = 0; i < tk; ++i) {
            float p = __uint_as_float((unsigned)(cand[i] >> 32));
            cum = cum + p;
            float excl = cum - p;
            float p1 = (excl <= topp) ? p : 0.f;
            float v = (p1 >= thrmp) ? p1 : 0.f;
            cdf += v;
            if (cdf > target) { sel = i; break; }
        }
        if (sel < 0) sel = 0;
        out[row] = (int)~(unsigned)cand[sel];
    }
}

extern "C" void kernel_launch(void* const* d_in, const int* in_sizes, int n_in,
                              void* d_out, int out_size, void* d_ws, size_t ws_size,
                              hipStream_t stream) {
    const float* logits = (const float*)d_in[0];
    const float* temps  = (const float*)d_in[1];
    const float* minps  = (const float*)d_in[2];
    const float* topps  = (const float*)d_in[3];
    const int*   topks  = (const int*)d_in[4];
    const float* us     = (const float*)d_in[5];
    const int B = in_sizes[1];
    const int V = in_sizes[0] / B;
    int* outp = (int*)d_out;

    const int slen = (((V + S - 1) / S) + 3) & ~3;   // slice length, mult of 4

    size_t need = 0;
    const size_t off_hist = need; need += (size_t)B * NB * sizeof(unsigned);
    const size_t off_max  = need; need += (size_t)B * S * sizeof(float);
    const size_t off_sum  = need; need += (size_t)B * S * sizeof(float);

    if (ws_size < need) {
        sampler_mono<<<dim3(B), dim3(FNT), 0, stream>>>(
            logits, temps, minps, topps, topks, us, outp, V);
        return;
    }

    char* w = (char*)d_ws;
    unsigned* ghist = (unsigned*)(w + off_hist);
    float*    gmax  = (float*)(w + off_max);
    float*    gsum  = (float*)(w + off_sum);

    // zero ghist (4 MB, 16B-aligned)
    {
        const int n16 = (int)(((size_t)B * NB * sizeof(unsigned)) / 16);
        k_zero<<<dim3(1024), dim3(256), 0, stream>>>((uint4*)ghist, n16);
    }

    k_pass1<<<dim3(S, B), dim3(NT1), 0, stream>>>(logits, temps, gmax, gsum, ghist, V, slen);
    k_finish2<<<dim3(B), dim3(NTF), 0, stream>>>(
        logits, ghist, gmax, gsum, temps, minps, topps, topks, us, outp, V);
}

// Round 11
// 79.571 us; speedup vs baseline: 1.1857x; 1.1857x over previous
//
#include <hip/hip_runtime.h>
#include <hip/hip_bf16.h>
#include <stdint.h>

typedef unsigned long long u64;

#define S 16            // slices per row
#define NB 8192         // candidate-histogram bins = top 13 bits of monotone key
#define KSHIFT 19       // 32-13
#define CAND_MAX 4096   // per-row candidate capacity
#define LCAP 1024       // per-slice candidate capacity (expect ~182)
#define SPEC_KEY 0xC0000000u   // fkey(2.0f): collect x >= 2.0 speculatively
#define OVF_FLAG 0x80000000u
#define NT1 256
#define NTF 1024
#define NWF (NTF / 64)
#define ITER1 8         // register-staged float4s per thread in pass1

__device__ __forceinline__ unsigned fkey(float x) {
    unsigned u = __float_as_uint(x);
    return ((int)u < 0) ? ~u : (u | 0x80000000u);
}

// ---------------- K0: fast zero for counters ----------------
__global__ __launch_bounds__(256) void k_zero(uint4* __restrict__ p, int n16)
{
    const uint4 z = make_uint4(0u, 0u, 0u, 0u);
    for (int i = blockIdx.x * 256 + threadIdx.x; i < n16; i += gridDim.x * 256)
        p[i] = z;
}

// ---------------- K1: single sweep: slice max + exp-sum + speculative collect ----
__global__ __launch_bounds__(NT1) void k_pass1(
    const float* __restrict__ logits, const float* __restrict__ temps,
    float* __restrict__ gmax, float* __restrict__ gsum,
    u64* __restrict__ gcand, unsigned* __restrict__ gpos,
    unsigned* __restrict__ gcnt, int V, int slen)
{
    const int s = blockIdx.x, b = blockIdx.y, tid = threadIdx.x;
    __shared__ u64 buf[LCAP];
    __shared__ float red[NT1 / 64];
    __shared__ float s_ms;
    __shared__ unsigned s_cnt, s_base;
    if (tid == 0) s_cnt = 0u;

    const float t = temps[b];
    const float* xrow = logits + (size_t)b * (size_t)V;
    const int beg = s * slen, end = min(V, beg + slen);
    const float4* x4 = (const float4*)xrow;
    const int beg4 = beg >> 2, end4 = end >> 2;
    const int reg_end = beg4 + ITER1 * NT1;

    float4 r[ITER1];
    #pragma unroll
    for (int k = 0; k < ITER1; ++k) {
        int idx = beg4 + k * NT1 + tid;
        r[k] = (idx < end4) ? x4[idx] : make_float4(-INFINITY, -INFINITY, -INFINITY, -INFINITY);
    }

    float lmax = -INFINITY;
    #pragma unroll
    for (int k = 0; k < ITER1; ++k)
        lmax = fmaxf(lmax, fmaxf(fmaxf(r[k].x, r[k].y), fmaxf(r[k].z, r[k].w)));
    for (int idx = reg_end + tid; idx < end4; idx += NT1) {
        float4 v = x4[idx];
        lmax = fmaxf(lmax, fmaxf(fmaxf(v.x, v.y), fmaxf(v.z, v.w)));
    }
    for (int i = max(beg, end4 << 2) + tid; i < end; i += NT1)
        lmax = fmaxf(lmax, xrow[i]);
    for (int off = 32; off > 0; off >>= 1) lmax = fmaxf(lmax, __shfl_xor(lmax, off));
    if ((tid & 63) == 0) red[tid >> 6] = lmax;
    __syncthreads();
    if (tid == 0) {
        float m = red[0];
        for (int w = 1; w < NT1 / 64; ++w) m = fmaxf(m, red[w]);
        gmax[b * S + s] = m;
        s_ms = m / t;
    }
    __syncthreads();
    const float ms = s_ms;

    float lsum = 0.f;
    #pragma unroll
    for (int k = 0; k < ITER1; ++k) {
        int idx = beg4 + k * NT1 + tid;
        if (idx < end4) {
            float e0 = expf(r[k].x / t - ms), e1 = expf(r[k].y / t - ms);
            float e2 = expf(r[k].z / t - ms), e3 = expf(r[k].w / t - ms);
            lsum += e0; lsum += e1; lsum += e2; lsum += e3;
            const int i0 = idx << 2;
            if (fkey(r[k].x) >= SPEC_KEY) { unsigned p = atomicAdd(&s_cnt, 1u); if (p < LCAP) buf[p] = ((u64)__float_as_uint(r[k].x) << 32) | (unsigned)(i0    ); }
            if (fkey(r[k].y) >= SPEC_KEY) { unsigned p = atomicAdd(&s_cnt, 1u); if (p < LCAP) buf[p] = ((u64)__float_as_uint(r[k].y) << 32) | (unsigned)(i0 + 1); }
            if (fkey(r[k].z) >= SPEC_KEY) { unsigned p = atomicAdd(&s_cnt, 1u); if (p < LCAP) buf[p] = ((u64)__float_as_uint(r[k].z) << 32) | (unsigned)(i0 + 2); }
            if (fkey(r[k].w) >= SPEC_KEY) { unsigned p = atomicAdd(&s_cnt, 1u); if (p < LCAP) buf[p] = ((u64)__float_as_uint(r[k].w) << 32) | (unsigned)(i0 + 3); }
        }
    }
    for (int idx = reg_end + tid; idx < end4; idx += NT1) {
        float4 v = x4[idx];
        float e0 = expf(v.x / t - ms), e1 = expf(v.y / t - ms);
        float e2 = expf(v.z / t - ms), e3 = expf(v.w / t - ms);
        lsum += e0; lsum += e1; lsum += e2; lsum += e3;
        const int i0 = idx << 2;
        if (fkey(v.x) >= SPEC_KEY) { unsigned p = atomicAdd(&s_cnt, 1u); if (p < LCAP) buf[p] = ((u64)__float_as_uint(v.x) << 32) | (unsigned)(i0    ); }
        if (fkey(v.y) >= SPEC_KEY) { unsigned p = atomicAdd(&s_cnt, 1u); if (p < LCAP) buf[p] = ((u64)__float_as_uint(v.y) << 32) | (unsigned)(i0 + 1); }
        if (fkey(v.z) >= SPEC_KEY) { unsigned p = atomicAdd(&s_cnt, 1u); if (p < LCAP) buf[p] = ((u64)__float_as_uint(v.z) << 32) | (unsigned)(i0 + 2); }
        if (fkey(v.w) >= SPEC_KEY) { unsigned p = atomicAdd(&s_cnt, 1u); if (p < LCAP) buf[p] = ((u64)__float_as_uint(v.w) << 32) | (unsigned)(i0 + 3); }
    }
    for (int i = max(beg, end4 << 2) + tid; i < end; i += NT1) {
        float x = xrow[i];
        float e = expf(x / t - ms);
        lsum += e;
        if (fkey(x) >= SPEC_KEY) { unsigned p = atomicAdd(&s_cnt, 1u); if (p < LCAP) buf[p] = ((u64)__float_as_uint(x) << 32) | (unsigned)i; }
    }
    for (int off = 32; off > 0; off >>= 1) lsum += __shfl_xor(lsum, off);
    if ((tid & 63) == 0) red[tid >> 6] = lsum;
    __syncthreads();
    if (tid == 0) {
        float sum = 0.f;
        for (int w = 0; w < NT1 / 64; ++w) sum += red[w];
        gsum[b * S + s] = sum;
        unsigned raw = s_cnt;
        unsigned capped = min(raw, (unsigned)LCAP);
        s_base = atomicAdd(&gpos[b], capped);
        atomicAdd(&gcnt[b], raw);
        if (raw > (unsigned)LCAP) atomicOr(&gcnt[b], OVF_FLAG);
        s_cnt = capped;
    }
    __syncthreads();
    const unsigned cnt = s_cnt, base = s_base;
    u64* dst = gcand + (size_t)b * CAND_MAX;
    for (unsigned i = tid; i < cnt; i += NT1) {
        unsigned p = base + i;
        if (p < CAND_MAX) dst[p] = buf[i];
    }
}

// ---------------- K2: per-row finish (fast: candidates only; slow: rescan) ------
__global__ __launch_bounds__(NTF) void k_finish(
    const float* __restrict__ logits, const u64* __restrict__ gcand,
    const unsigned* __restrict__ gpos, const unsigned* __restrict__ gcnt,
    const float* __restrict__ gmax, const float* __restrict__ gsum,
    const float* __restrict__ temps, const float* __restrict__ minps,
    const float* __restrict__ topps, const int* __restrict__ topks,
    const float* __restrict__ us, int* __restrict__ out, int V)
{
    const int b = blockIdx.x, tid = threadIdx.x;
    __shared__ u64 cand[CAND_MAX];
    __shared__ unsigned h[NB];
    __shared__ float wsum[NWF];
    __shared__ unsigned wfirst[NWF];
    __shared__ float s_m, s_den;
    __shared__ unsigned s_thr, s_cnt;

    const float t = temps[b];
    const int tk0 = topks[b];

    // wave 0: row max + denom from slice partials
    if (tid < 64) {
        const int lane = tid;
        float v = (lane < S) ? gmax[b * S + lane] : -INFINITY;
        float vv = v;
        for (int off = 32; off > 0; off >>= 1) vv = fmaxf(vv, __shfl_xor(vv, off));
        const float m = vv / t;
        float d = (lane < S) ? gsum[b * S + lane] * expf(v / t - m) : 0.f;
        for (int off = 32; off > 0; off >>= 1) d += __shfl_xor(d, off);
        if (lane == 0) { s_m = m; s_den = d; }
    }
    for (int i = tid; i < NB; i += NTF) h[i] = 0u;
    if (tid == 0) s_cnt = 0u;
    __syncthreads();
    const float m = s_m, denom = s_den;

    const unsigned cntraw = gcnt[b];
    const bool fast = !(cntraw & OVF_FLAG) && cntraw <= (unsigned)CAND_MAX
                      && cntraw >= (unsigned)tk0 && cntraw > 0u;

    if (fast) {
        const int n_all = (int)cntraw;             // == gpos[b], no drops
        const u64* src = gcand + (size_t)b * CAND_MAX;
        u64 myc[CAND_MAX / NTF];
        #pragma unroll
        for (int k = 0; k < CAND_MAX / NTF; ++k) {
            int idx = tid + k * NTF;
            myc[k] = 0ULL;
            if (idx < n_all) {
                u64 w = src[idx];
                myc[k] = w;
                unsigned key = ((unsigned)(w >> 32)) | 0x80000000u;  // x>=2 -> positive bits
                atomicAdd(&h[key >> KSHIFT], 1u);
            }
        }
        __syncthreads();
        // wave 0: suffix scan over candidate histogram, threshold covering tk0
        if (tid < 64) {
            const int lane = tid;
            const unsigned needed = (unsigned)tk0;
            const int CH = NB / 64;
            const int base = lane * CH;
            unsigned c = 0;
            for (int j = 0; j < CH; ++j) c += h[base + j];
            unsigned tsuf = c;
            for (int off = 1; off < 64; off <<= 1) {
                unsigned o = __shfl_down(tsuf, off);
                if (lane + off < 64) tsuf += o;
            }
            u64 mask = __ballot(tsuf >= needed);
            int lstar = 63 - __builtin_clzll(mask);
            unsigned above = __shfl(tsuf, (lstar + 1) & 63);
            if (lstar == 63) above = 0u;
            if (lane == 0) {
                unsigned run = above;
                int thrbin = lstar * CH;
                for (int bb = lstar * CH + CH - 1; bb >= lstar * CH; --bb) {
                    run += h[bb];
                    if (run >= needed) { thrbin = bb; break; }
                }
                s_thr = (unsigned)thrbin << KSHIFT;
            }
        }
        __syncthreads();
        const unsigned thr = s_thr;
        // compact survivors + exp + repack to (p_bits, ~idx)
        #pragma unroll
        for (int k = 0; k < CAND_MAX / NTF; ++k) {
            int idx = tid + k * NTF;
            if (idx < n_all) {
                unsigned ub = (unsigned)(myc[k] >> 32);
                unsigned key = ub | 0x80000000u;
                if (key >= thr) {
                    float x = __uint_as_float(ub);
                    float p = expf(x / t - m) / denom;
                    unsigned pos = atomicAdd(&s_cnt, 1u);
                    if (pos < CAND_MAX)
                        cand[pos] = ((u64)__float_as_uint(p) << 32) | (unsigned)(~(unsigned)myc[k]);
                }
            }
        }
        __syncthreads();
    } else {
        // ---- slow path: full-row hist + rescan (adversarial inputs only) ----
        const float* xrow = logits + (size_t)b * (size_t)V;
        const float4* x4 = (const float4*)xrow;
        const int n4 = V >> 2;
        for (int i = tid; i < n4; i += NTF) {
            float4 v = x4[i];
            atomicAdd(&h[fkey(v.x) >> KSHIFT], 1u);
            atomicAdd(&h[fkey(v.y) >> KSHIFT], 1u);
            atomicAdd(&h[fkey(v.z) >> KSHIFT], 1u);
            atomicAdd(&h[fkey(v.w) >> KSHIFT], 1u);
        }
        for (int i = (n4 << 2) + tid; i < V; i += NTF)
            atomicAdd(&h[fkey(xrow[i]) >> KSHIFT], 1u);
        __syncthreads();
        if (tid < 64) {
            const int lane = tid;
            const unsigned needed = (unsigned)tk0;
            const int CH = NB / 64;
            const int base = lane * CH;
            unsigned c = 0;
            for (int j = 0; j < CH; ++j) c += h[base + j];
            unsigned tsuf = c;
            for (int off = 1; off < 64; off <<= 1) {
                unsigned o = __shfl_down(tsuf, off);
                if (lane + off < 64) tsuf += o;
            }
            u64 mask = __ballot(tsuf >= needed);
            int lstar = 63 - __builtin_clzll(mask);
            unsigned above = __shfl(tsuf, (lstar + 1) & 63);
            if (lstar == 63) above = 0u;
            if (lane == 0) {
                unsigned run = above;
                int thrbin = lstar * CH;
                for (int bb = lstar * CH + CH - 1; bb >= lstar * CH; --bb) {
                    run += h[bb];
                    if (run >= needed) { thrbin = bb; break; }
                }
                s_thr = (unsigned)thrbin << KSHIFT;
            }
        }
        __syncthreads();
        const unsigned thr = s_thr;
        for (int i = tid; i < n4; i += NTF) {
            float4 v = x4[i];
            const int i0 = i << 2;
            #pragma unroll
            for (int c = 0; c < 4; ++c) {
                float x = (c == 0) ? v.x : (c == 1) ? v.y : (c == 2) ? v.z : v.w;
                if (fkey(x) >= thr) {
                    float p = expf(x / t - m) / denom;
                    unsigned pos = atomicAdd(&s_cnt, 1u);
                    if (pos < CAND_MAX)
                        cand[pos] = ((u64)__float_as_uint(p) << 32) | (unsigned)(~(unsigned)(i0 + c));
                }
            }
        }
        for (int i = (n4 << 2) + tid; i < V; i += NTF) {
            float x = xrow[i];
            if (fkey(x) >= thr) {
                float p = expf(x / t - m) / denom;
                unsigned pos = atomicAdd(&s_cnt, 1u);
                if (pos < CAND_MAX)
                    cand[pos] = ((u64)__float_as_uint(p) << 32) | (unsigned)(~(unsigned)i);
            }
        }
        __syncthreads();
    }

    int n = (int)min(s_cnt, (unsigned)CAND_MAX);
    int n2 = 1; while (n2 < n) n2 <<= 1;
    for (int i = n + tid; i < n2; i += NTF) cand[i] = 0ULL;
    __syncthreads();

    // bitonic sort, descending by (p_bits, ~idx)
    for (int k = 2; k <= n2; k <<= 1) {
        for (int j = k >> 1; j > 0; j >>= 1) {
            for (int i = tid; i < n2; i += NTF) {
                int ixj = i ^ j;
                if (ixj > i) {
                    u64 a = cand[i], bb = cand[ixj];
                    bool sw = ((i & k) == 0) ? (a < bb) : (a > bb);
                    if (sw) { cand[i] = bb; cand[ixj] = a; }
                }
            }
            __syncthreads();
        }
    }

    // parallel epilogue: thread i owns sorted element i
    const int lane = tid & 63, wv = tid >> 6;
    const float topp = topps[b], minp = minps[b], uu = us[b];
    int tk = tk0;
    if (tk > n) tk = n;
    if (tk > NTF) tk = NTF;

    float p = 0.f;
    if (tid < tk) p = __uint_as_float((unsigned)(cand[tid] >> 32));

    float c = p;
    #pragma unroll
    for (int off = 1; off < 64; off <<= 1) {
        float o = __shfl_up(c, off);
        if (lane >= off) c += o;
    }
    if (lane == 63) wsum[wv] = c;
    __syncthreads();
    if (tid < 64) {
        float sv = (tid < NWF) ? wsum[tid] : 0.f;
        #pragma unroll
        for (int off = 1; off < NWF; off <<= 1) {
            float o = __shfl_up(sv, off);
            if (tid >= off) sv += o;
        }
        if (tid < NWF) wsum[tid] = sv;
    }
    __syncthreads();
    float cum = c + ((wv > 0) ? wsum[wv - 1] : 0.f);
    float excl = cum - p;                       // replicate (cumsum - p) rounding shape
    float p0 = __uint_as_float((unsigned)(cand[0] >> 32));
    float thrmp = p0 * minp;
    float p1v = (excl <= topp) ? p : 0.f;
    float v = (p1v >= thrmp) ? p1v : 0.f;
    __syncthreads();

    float cv = v;
    #pragma unroll
    for (int off = 1; off < 64; off <<= 1) {
        float o = __shfl_up(cv, off);
        if (lane >= off) cv += o;
    }
    if (lane == 63) wsum[wv] = cv;
    __syncthreads();
    if (tid < 64) {
        float sv = (tid < NWF) ? wsum[tid] : 0.f;
        #pragma unroll
        for (int off = 1; off < NWF; off <<= 1) {
            float o = __shfl_up(sv, off);
            if (tid >= off) sv += o;
        }
        if (tid < NWF) wsum[tid] = sv;
    }
    __syncthreads();
    float cdf = cv + ((wv > 0) ? wsum[wv - 1] : 0.f);
    float total = wsum[NWF - 1];
    float target = uu * total;

    bool hit = (tid < tk) && (cdf > target);
    u64 mk = __ballot(hit);
    if (lane == 0) wfirst[wv] = mk ? (unsigned)__builtin_ctzll(mk) : 0xFFFFFFFFu;
    __syncthreads();
    if (tid == 0) {
        int sel = -1;
        for (int w = 0; w < NWF; ++w)
            if (wfirst[w] != 0xFFFFFFFFu) { sel = w * 64 + (int)wfirst[w]; break; }
        if (sel < 0) sel = 0;
        out[b] = (int)~(unsigned)cand[sel];
    }
}

// ---------------- Fallback: monolithic single kernel (round-1, passed) ----------------
#define FNT 512
#define FNBINS 1024
#define FKMARGIN 1224
__global__ __launch_bounds__(FNT) void sampler_mono(
    const float* __restrict__ logits, const float* __restrict__ temps,
    const float* __restrict__ minps, const float* __restrict__ topps,
    const int* __restrict__ topks, const float* __restrict__ us,
    int* __restrict__ out, int V)
{
    const int row = blockIdx.x;
    const int tid = threadIdx.x;
    const float t = temps[row];
    __shared__ unsigned int hist[FNBINS];
    __shared__ u64 cand[CAND_MAX];
    __shared__ float red[FNT / 64];
    __shared__ float s_m, s_denom;
    __shared__ unsigned s_thr, s_cnt;
    for (int i = tid; i < FNBINS; i += FNT) hist[i] = 0u;
    if (tid == 0) s_cnt = 0u;
    const float* xrow = logits + (size_t)row * (size_t)V;
    const int n4 = V >> 2;
    const float4* x4 = (const float4*)xrow;
    float lmax = -INFINITY;
    for (int i = tid; i < n4; i += FNT) {
        float4 v = x4[i];
        lmax = fmaxf(lmax, fmaxf(fmaxf(v.x, v.y), fmaxf(v.z, v.w)));
    }
    for (int i = (n4 << 2) + tid; i < V; i += FNT) lmax = fmaxf(lmax, xrow[i]);
    for (int off = 32; off > 0; off >>= 1) lmax = fmaxf(lmax, __shfl_xor(lmax, off));
    if ((tid & 63) == 0) red[tid >> 6] = lmax;
    __syncthreads();
    if (tid == 0) {
        float r = red[0];
        for (int w = 1; w < FNT / 64; ++w) r = fmaxf(r, red[w]);
        s_m = r / t;
    }
    __syncthreads();
    const float m = s_m;
    float lsum = 0.f;
    for (int i = tid; i < n4; i += FNT) {
        float4 v = x4[i];
        float e0 = expf(v.x / t - m), e1 = expf(v.y / t - m);
        float e2 = expf(v.z / t - m), e3 = expf(v.w / t - m);
        lsum += e0; lsum += e1; lsum += e2; lsum += e3;
        atomicAdd(&hist[__float_as_uint(e0) >> 20], 1u);
        atomicAdd(&hist[__float_as_uint(e1) >> 20], 1u);
        atomicAdd(&hist[__float_as_uint(e2) >> 20], 1u);
        atomicAdd(&hist[__float_as_uint(e3) >> 20], 1u);
    }
    for (int i = (n4 << 2) + tid; i < V; i += FNT) {
        float e = expf(xrow[i] / t - m);
        lsum += e;
        atomicAdd(&hist[__float_as_uint(e) >> 20], 1u);
    }
    for (int off = 32; off > 0; off >>= 1) lsum += __shfl_xor(lsum, off);
    if ((tid & 63) == 0) red[tid >> 6] = lsum;
    __syncthreads();
    if (tid == 0) {
        float r = 0.f;
        for (int w = 0; w < FNT / 64; ++w) r += red[w];
        s_denom = r;
    }
    __syncthreads();
    const float denom = s_denom;
    if (tid < 64) {
        const int lane = tid;
        const int CH = FNBINS / 64;
        const int base = lane * CH;
        unsigned c = 0;
        #pragma unroll
        for (int j = 0; j < CH; ++j) c += hist[base + j];
        unsigned tsuf = c;
        #pragma unroll
        for (int off = 1; off < 64; off <<= 1) {
            unsigned o = __shfl_down(tsuf, off);
            if (lane + off < 64) tsuf += o;
        }
        unsigned long long mask = __ballot(tsuf >= (unsigned)FKMARGIN);
        int lstar = 63 - __builtin_clzll(mask);
        unsigned above = __shfl(tsuf, (lstar + 1) & 63);
        if (lstar == 63) above = 0u;
        if (lane == 0) {
            unsigned run = above;
            int thrbin = lstar * CH;
            for (int bb = lstar * CH + CH - 1; bb >= lstar * CH; --bb) {
                run += hist[bb];
                if (run >= (unsigned)FKMARGIN) { thrbin = bb; break; }
            }
            s_thr = (unsigned)thrbin << 20;
        }
    }
    __syncthreads();
    const unsigned thrkey = s_thr;
    for (int i = tid; i < n4; i += FNT) {
        float4 v = x4[i];
        float e[4] = { expf(v.x / t - m), expf(v.y / t - m),
                       expf(v.z / t - m), expf(v.w / t - m) };
        #pragma unroll
        for (int c = 0; c < 4; ++c) {
            unsigned eb = __float_as_uint(e[c]);
            if (eb >= thrkey) {
                float p = e[c] / denom;
                unsigned pos = atomicAdd(&s_cnt, 1u);
                if (pos < CAND_MAX)
                    cand[pos] = ((u64)__float_as_uint(p) << 32) | (unsigned)(~(unsigned)((i << 2) + c));
            }
        }
    }
    for (int i = (n4 << 2) + tid; i < V; i += FNT) {
        float e = expf(xrow[i] / t - m);
        if (__float_as_uint(e) >= thrkey) {
            float p = e / denom;
            unsigned pos = atomicAdd(&s_cnt, 1u);
            if (pos < CAND_MAX)
                cand[pos] = ((u64)__float_as_uint(p) << 32) | (unsigned)(~(unsigned)i);
        }
    }
    __syncthreads();
    int n = (int)s_cnt; if (n > CAND_MAX) n = CAND_MAX;
    int n2 = 1; while (n2 < n) n2 <<= 1;
    for (int i = n + tid; i < n2; i += FNT) cand[i] = 0ULL;
    __syncthreads();
    for (int k = 2; k <= n2; k <<= 1) {
        for (int j = k >> 1; j > 0; j >>= 1) {
            for (int i = tid; i < n2; i += FNT) {
                int ixj = i ^ j;
                if (ixj > i) {
                    u64 a = cand[i], bb = cand[ixj];
                    bool sw = ((i & k) == 0) ? (a < bb) : (a > bb);
                    if (sw) { cand[i] = bb; cand[ixj] = a; }
                }
            }
            __syncthreads();
        }
    }
    if (tid == 0) {
        const float topp = topps[row], minp = minps[row], uu = us[row];
        int tk = topks[row];
        if (tk > n) tk = n;
        float p0 = __uint_as_float((unsigned)(cand[0] >> 32));
        float thrmp = p0 * minp;
        float cum = 0.f, total = 0.f;
        for (int i = 0; i < tk; ++i) {
            float p = __uint_as_float((unsigned)(cand[i] >> 32));
            cum = cum + p;
            float excl = cum - p;
            float p1 = (excl <= topp) ? p : 0.f;
            float v = (p1 >= thrmp) ? p1 : 0.f;
            total += v;
        }
        float target = uu * total;
        float cdf = 0.f; int sel = -1;
        cum = 0.f;
        for (int i = 0; i < tk; ++i) {
            float p = __uint_as_float((unsigned)(cand[i] >> 32));
            cum = cum + p;
            float excl = cum - p;
            float p1 = (excl <= topp) ? p : 0.f;
            float v = (p1 >= thrmp) ? p1 : 0.f;
            cdf += v;
            if (cdf > target) { sel = i; break; }
        }
        if (sel < 0) sel = 0;
        out[row] = (int)~(unsigned)cand[sel];
    }
}

extern "C" void kernel_launch(void* const* d_in, const int* in_sizes, int n_in,
                              void* d_out, int out_size, void* d_ws, size_t ws_size,
                              hipStream_t stream) {
    const float* logits = (const float*)d_in[0];
    const float* temps  = (const float*)d_in[1];
    const float* minps  = (const float*)d_in[2];
    const float* topps  = (const float*)d_in[3];
    const int*   topks  = (const int*)d_in[4];
    const float* us     = (const float*)d_in[5];
    const int B = in_sizes[1];
    const int V = in_sizes[0] / B;
    int* outp = (int*)d_out;

    const int slen = (((V + S - 1) / S) + 3) & ~3;   // slice length, mult of 4

    size_t need = 0;
    const size_t off_cand = need; need += (size_t)B * CAND_MAX * sizeof(u64);
    const size_t off_pos  = need; need += (size_t)B * sizeof(unsigned);
    const size_t off_cnt  = need; need += (size_t)B * sizeof(unsigned);
    const size_t off_max  = need; need += (size_t)B * S * sizeof(float);
    const size_t off_sum  = need; need += (size_t)B * S * sizeof(float);

    if (ws_size < need) {
        sampler_mono<<<dim3(B), dim3(FNT), 0, stream>>>(
            logits, temps, minps, topps, topks, us, outp, V);
        return;
    }

    char* w = (char*)d_ws;
    u64*      gcand = (u64*)(w + off_cand);
    unsigned* gpos  = (unsigned*)(w + off_pos);
    unsigned* gcnt  = (unsigned*)(w + off_cnt);
    float*    gmax  = (float*)(w + off_max);
    float*    gsum  = (float*)(w + off_sum);

    // zero gpos+gcnt (contiguous, 2*B*4 bytes, 16B-aligned)
    {
        const int n16 = (int)((2 * (size_t)B * sizeof(unsigned)) / 16);
        k_zero<<<dim3(4), dim3(256), 0, stream>>>((uint4*)gpos, n16);
    }

    k_pass1<<<dim3(S, B), dim3(NT1), 0, stream>>>(
        logits, temps, gmax, gsum, gcand, gpos, gcnt, V, slen);
    k_finish<<<dim3(B), dim3(NTF), 0, stream>>>(
        logits, gcand, gpos, gcnt, gmax, gsum, temps, minps, topps, topks, us, outp, V);
}

// Round 12
// 44.050 us; speedup vs baseline: 2.1418x; 1.8064x over previous
//
#include <hip/hip_runtime.h>
#include <hip/hip_bf16.h>
#include <stdint.h>

typedef unsigned long long u64;

#define S 16            // slices per row
#define NBF 8192        // fine bins for counting sort (range [2,8), width 2^24>>11)
#define KBASE 0xC0000000u   // fkey(2.0f)
#define FSHIFT 11
#define KSHIFT 19       // coarse 13-bit key (slow path)
#define CAND_MAX 4096
#define LCAP 1024       // per-slice spec capacity (expect ~182)
#define SPEC_KEY 0xC0000000u   // collect x >= 2.0
#define OVF_FLAG 0x80000000u
#define NT1 256
#define NW1 (NT1 / 64)
#define NTF 1024
#define NWF (NTF / 64)

__device__ __forceinline__ unsigned fkey(float x) {
    unsigned u = __float_as_uint(x);
    return ((int)u < 0) ? ~u : (u | 0x80000000u);
}

// ---------------- K0: zero counters ----------------
__global__ __launch_bounds__(256) void k_zero(uint4* __restrict__ p, int n16)
{
    const uint4 z = make_uint4(0u, 0u, 0u, 0u);
    for (int i = blockIdx.x * 256 + threadIdx.x; i < n16; i += gridDim.x * 256)
        p[i] = z;
}

// ---------------- K1: single sweep: max + raw exp-sum + speculative collect ----
__global__ __launch_bounds__(NT1) void k_pass1(
    const float* __restrict__ logits, const float* __restrict__ temps,
    float* __restrict__ gmax, float* __restrict__ gsum,
    u64* __restrict__ gcand, unsigned* __restrict__ gpos,
    unsigned* __restrict__ gcnt, int V, int slen)
{
    const int s = blockIdx.x, b = blockIdx.y, tid = threadIdx.x;
    __shared__ u64 buf[LCAP];
    __shared__ float redm[NW1], reds[NW1];
    __shared__ unsigned s_cnt, s_base;
    if (tid == 0) s_cnt = 0u;
    __syncthreads();

    const float t = temps[b];
    const float invt = 1.0f / t;      // denom-only path; rounding class accepted
    const float* xrow = logits + (size_t)b * (size_t)V;
    const int beg = s * slen, end = min(V, beg + slen);
    const float4* x4 = (const float4*)xrow;
    const int beg4 = beg >> 2, end4 = end >> 2;

    float lmax = -INFINITY, lsum = 0.f;
    for (int idx = beg4 + tid; idx < end4; idx += NT1) {
        float4 v = x4[idx];
        lmax = fmaxf(lmax, fmaxf(fmaxf(v.x, v.y), fmaxf(v.z, v.w)));
        lsum += expf(v.x * invt); lsum += expf(v.y * invt);
        lsum += expf(v.z * invt); lsum += expf(v.w * invt);
        const int i0 = idx << 2;
        if (fkey(v.x) >= SPEC_KEY) { unsigned p = atomicAdd(&s_cnt, 1u); if (p < LCAP) buf[p] = ((u64)__float_as_uint(v.x) << 32) | (unsigned)(i0    ); }
        if (fkey(v.y) >= SPEC_KEY) { unsigned p = atomicAdd(&s_cnt, 1u); if (p < LCAP) buf[p] = ((u64)__float_as_uint(v.y) << 32) | (unsigned)(i0 + 1); }
        if (fkey(v.z) >= SPEC_KEY) { unsigned p = atomicAdd(&s_cnt, 1u); if (p < LCAP) buf[p] = ((u64)__float_as_uint(v.z) << 32) | (unsigned)(i0 + 2); }
        if (fkey(v.w) >= SPEC_KEY) { unsigned p = atomicAdd(&s_cnt, 1u); if (p < LCAP) buf[p] = ((u64)__float_as_uint(v.w) << 32) | (unsigned)(i0 + 3); }
    }
    for (int i = max(beg, end4 << 2) + tid; i < end; i += NT1) {
        float x = xrow[i];
        lmax = fmaxf(lmax, x);
        lsum += expf(x * invt);
        if (fkey(x) >= SPEC_KEY) { unsigned p = atomicAdd(&s_cnt, 1u); if (p < LCAP) buf[p] = ((u64)__float_as_uint(x) << 32) | (unsigned)i; }
    }

    for (int off = 32; off > 0; off >>= 1) {
        lmax = fmaxf(lmax, __shfl_xor(lmax, off));
        lsum += __shfl_xor(lsum, off);
    }
    if ((tid & 63) == 0) { redm[tid >> 6] = lmax; reds[tid >> 6] = lsum; }
    __syncthreads();
    if (tid == 0) {
        float m = redm[0], sum = reds[0];
        for (int w = 1; w < NW1; ++w) { m = fmaxf(m, redm[w]); sum += reds[w]; }
        gmax[b * S + s] = m;
        gsum[b * S + s] = sum;            // raw sum of expf(x/t), no max shift
        unsigned raw = s_cnt;
        unsigned capped = min(raw, (unsigned)LCAP);
        s_base = atomicAdd(&gpos[b], capped);
        atomicAdd(&gcnt[b], raw);
        if (raw > (unsigned)LCAP) atomicOr(&gcnt[b], OVF_FLAG);
        s_cnt = capped;
    }
    __syncthreads();
    const unsigned cnt = s_cnt, base = s_base;
    u64* dst = gcand + (size_t)b * CAND_MAX;
    for (unsigned i = tid; i < cnt; i += NT1) {
        unsigned p = base + i;
        if (p < CAND_MAX) dst[p] = buf[i];
    }
}

// ---------------- K2: per-row finish: counting sort (fast) / rescan+bitonic (slow) ----
__global__ __launch_bounds__(NTF) void k_finish(
    const float* __restrict__ logits, const u64* __restrict__ gcand,
    const unsigned* __restrict__ gcnt,
    const float* __restrict__ gmax, const float* __restrict__ gsum,
    const float* __restrict__ temps, const float* __restrict__ minps,
    const float* __restrict__ topps, const int* __restrict__ topks,
    const float* __restrict__ us, int* __restrict__ out, int V)
{
    const int b = blockIdx.x, tid = threadIdx.x;
    __shared__ u64 cand[CAND_MAX];
    __shared__ unsigned h[NBF + 1];
    __shared__ float wsum[NWF];
    __shared__ unsigned wfirst[NWF];
    __shared__ float s_m, s_den;
    __shared__ int s_thri;
    __shared__ unsigned s_cnt, s_n;

    const float t = temps[b];
    const int tk0 = topks[b];
    const unsigned tk0u = (unsigned)tk0;

    // wave 0: row max + denom from slice partials (denom = e^{-m} * sum_raw)
    if (tid < 64) {
        const int lane = tid;
        float v = (lane < S) ? gmax[b * S + lane] : -INFINITY;
        float vv = v;
        for (int off = 32; off > 0; off >>= 1) vv = fmaxf(vv, __shfl_xor(vv, off));
        const float m = vv / t;
        float d = (lane < S) ? gsum[b * S + lane] * expf(-m) : 0.f;
        for (int off = 32; off > 0; off >>= 1) d += __shfl_xor(d, off);
        if (lane == 0) { s_m = m; s_den = d; }
    }
    for (int i = tid; i <= NBF; i += NTF) h[i] = 0u;
    if (tid == 0) { s_cnt = 0u; s_thri = -1; }
    __syncthreads();
    const float m = s_m, denom = s_den;

    const unsigned cntraw = gcnt[b];
    const bool fast = !(cntraw & OVF_FLAG) && cntraw <= (unsigned)CAND_MAX
                      && cntraw >= tk0u && cntraw > 0u
                      && isfinite(denom) && denom > 0.f;

    int n;
    if (fast) {
        // ---- candidates -> registers + fine histogram ----
        const int n_all = (int)cntraw;
        const u64* src = gcand + (size_t)b * CAND_MAX;
        u64 myc[CAND_MAX / NTF];
        int mykf[CAND_MAX / NTF];
        #pragma unroll
        for (int k = 0; k < CAND_MAX / NTF; ++k) {
            int idx = tid + k * NTF;
            myc[k] = 0ULL; mykf[k] = -1;
            if (idx < n_all) {
                u64 w = src[idx];
                myc[k] = w;
                unsigned fk = ((unsigned)(w >> 32)) | 0x80000000u;  // fkey (x>0)
                unsigned kf = (fk - KBASE) >> FSHIFT;
                if (kf > (unsigned)(NBF - 1)) kf = NBF - 1;
                mykf[k] = (int)kf;
                atomicAdd(&h[kf], 1u);
            }
        }
        __syncthreads();

        // ---- block suffix-scan over h[0..NBF): h[bin] <- sum_{b'>bin} cnt ----
        const int lane = tid & 63, wv = tid >> 6;
        unsigned cnt8[8];
        const int b0 = tid * 8;
        unsigned L = 0;
        #pragma unroll
        for (int j = 0; j < 8; ++j) { cnt8[j] = h[b0 + j]; L += cnt8[j]; }
        unsigned tsuf = L;
        #pragma unroll
        for (int off = 1; off < 64; off <<= 1) {
            unsigned o = __shfl_down(tsuf, off);
            if (lane + off < 64) tsuf += o;
        }
        if (lane == 0) wfirst[wv] = tsuf;
        __syncthreads();
        if (tid < 64) {
            unsigned sv = (tid < NWF) ? wfirst[tid] : 0u;
            #pragma unroll
            for (int off = 1; off < NWF; off <<= 1) {
                unsigned o = __shfl_down(sv, off);
                if (tid + off < NWF) sv += o;
            }
            if (tid < NWF) wfirst[tid] = sv;   // inclusive suffix of wave sums
        }
        __syncthreads();
        unsigned above = tsuf - L + ((wv + 1 < NWF) ? wfirst[wv + 1] : 0u);
        // rewrite starts (desc order: higher bin -> lower offset), find thr bin
        unsigned run = above;
        int mythr = -1;
        #pragma unroll
        for (int j = 7; j >= 0; --j) {
            unsigned incl = run + cnt8[j];
            if (mythr < 0 && incl >= tk0u) mythr = b0 + j;
            h[b0 + j] = run;
            run = incl;
        }
        __syncthreads();   // all starts written before atomicMax readers proceed
        if (mythr >= 0) atomicMax(&s_thri, mythr);
        __syncthreads();
        const int thrbin = s_thri;
        if ((thrbin >> 3) == tid) s_n = h[thrbin] + cnt8[thrbin & 7];
        __syncthreads();
        n = (int)s_n;

        // ---- scatter: p = exp(x/t - m)/denom, dest via per-bin atomic ----
        #pragma unroll
        for (int k = 0; k < CAND_MAX / NTF; ++k) {
            if (mykf[k] >= thrbin) {
                unsigned ub = (unsigned)(myc[k] >> 32);
                float x = __uint_as_float(ub);
                float p = expf(x / t - m) / denom;
                unsigned dest = atomicAdd(&h[mykf[k]], 1u);
                if (dest < (unsigned)CAND_MAX)
                    cand[dest] = ((u64)__float_as_uint(p) << 32) | (unsigned)(~(unsigned)myc[k]);
            }
        }
        __syncthreads();

        // ---- fixup: insertion-sort multi-element bins (desc by composite) ----
        for (int bb = thrbin + tid; bb < NBF; bb += NTF) {
            unsigned endo = h[bb];          // post-scatter = start + cnt
            unsigned starto = h[bb + 1];    // = start of bin bb
            if (endo > starto + 1 && starto < tk0u) {
                for (unsigned ii = starto + 1; ii < endo; ++ii) {
                    u64 key = cand[ii];
                    unsigned jj = ii;
                    while (jj > starto && cand[jj - 1] < key) { cand[jj] = cand[jj - 1]; --jj; }
                    cand[jj] = key;
                }
            }
        }
        __syncthreads();
    } else {
        // ---- slow path (adversarial only): full hist + denom + rescan + bitonic ----
        const int lane = tid & 63, wv = tid >> 6;
        const float* xrow = logits + (size_t)b * (size_t)V;
        const float4* x4 = (const float4*)xrow;
        const int n4 = V >> 2;
        float lsum = 0.f;
        for (int i = tid; i < n4; i += NTF) {
            float4 v = x4[i];
            lsum += expf(v.x / t - m); lsum += expf(v.y / t - m);
            lsum += expf(v.z / t - m); lsum += expf(v.w / t - m);
            atomicAdd(&h[fkey(v.x) >> KSHIFT], 1u);
            atomicAdd(&h[fkey(v.y) >> KSHIFT], 1u);
            atomicAdd(&h[fkey(v.z) >> KSHIFT], 1u);
            atomicAdd(&h[fkey(v.w) >> KSHIFT], 1u);
        }
        for (int i = (n4 << 2) + tid; i < V; i += NTF) {
            lsum += expf(xrow[i] / t - m);
            atomicAdd(&h[fkey(xrow[i]) >> KSHIFT], 1u);
        }
        for (int off = 32; off > 0; off >>= 1) lsum += __shfl_xor(lsum, off);
        if (lane == 0) wsum[wv] = lsum;
        __syncthreads();
        if (tid == 0) {
            float d = 0.f;
            for (int w = 0; w < NWF; ++w) d += wsum[w];
            s_den = d;
        }
        __syncthreads();
        const float den2 = s_den;
        if (tid < 64) {
            const unsigned needed = tk0u;
            const int CH = NBF / 64;
            const int base = tid * CH;
            unsigned c = 0;
            for (int j = 0; j < CH; ++j) c += h[base + j];
            unsigned tsuf = c;
            for (int off = 1; off < 64; off <<= 1) {
                unsigned o = __shfl_down(tsuf, off);
                if (tid + off < 64) tsuf += o;
            }
            u64 mask = __ballot(tsuf >= needed);
            int lstar = 63 - __builtin_clzll(mask);
            unsigned above = __shfl(tsuf, (lstar + 1) & 63);
            if (lstar == 63) above = 0u;
            if (tid == 0) {
                unsigned run = above;
                int thrb = lstar * CH;
                for (int bb2 = lstar * CH + CH - 1; bb2 >= lstar * CH; --bb2) {
                    run += h[bb2];
                    if (run >= needed) { thrb = bb2; break; }
                }
                s_thri = thrb;
            }
        }
        __syncthreads();
        const unsigned thr = (unsigned)s_thri << KSHIFT;
        for (int i = tid; i < n4; i += NTF) {
            float4 v = x4[i];
            const int i0 = i << 2;
            #pragma unroll
            for (int c = 0; c < 4; ++c) {
                float x = (c == 0) ? v.x : (c == 1) ? v.y : (c == 2) ? v.z : v.w;
                if (fkey(x) >= thr) {
                    float p = expf(x / t - m) / den2;
                    unsigned pos = atomicAdd(&s_cnt, 1u);
                    if (pos < CAND_MAX)
                        cand[pos] = ((u64)__float_as_uint(p) << 32) | (unsigned)(~(unsigned)(i0 + c));
                }
            }
        }
        for (int i = (n4 << 2) + tid; i < V; i += NTF) {
            float x = xrow[i];
            if (fkey(x) >= thr) {
                float p = expf(x / t - m) / den2;
                unsigned pos = atomicAdd(&s_cnt, 1u);
                if (pos < CAND_MAX)
                    cand[pos] = ((u64)__float_as_uint(p) << 32) | (unsigned)(~(unsigned)i);
            }
        }
        __syncthreads();
        n = (int)min(s_cnt, (unsigned)CAND_MAX);
        int n2 = 1; while (n2 < n) n2 <<= 1;
        for (int i = n + tid; i < n2; i += NTF) cand[i] = 0ULL;
        __syncthreads();
        for (int k = 2; k <= n2; k <<= 1) {
            for (int j = k >> 1; j > 0; j >>= 1) {
                for (int i = tid; i < n2; i += NTF) {
                    int ixj = i ^ j;
                    if (ixj > i) {
                        u64 a = cand[i], bb2 = cand[ixj];
                        bool sw = ((i & k) == 0) ? (a < bb2) : (a > bb2);
                        if (sw) { cand[i] = bb2; cand[ixj] = a; }
                    }
                }
                __syncthreads();
            }
        }
    }

    // ---- parallel epilogue: thread i owns sorted element i ----
    const int lane = tid & 63, wv = tid >> 6;
    const float topp = topps[b], minp = minps[b], uu = us[b];
    int tk = tk0;
    if (tk > n) tk = n;
    if (tk > NTF) tk = NTF;

    float p = 0.f;
    if (tid < tk) p = __uint_as_float((unsigned)(cand[tid] >> 32));

    float c = p;
    #pragma unroll
    for (int off = 1; off < 64; off <<= 1) {
        float o = __shfl_up(c, off);
        if (lane >= off) c += o;
    }
    if (lane == 63) wsum[wv] = c;
    __syncthreads();
    if (tid < 64) {
        float sv = (tid < NWF) ? wsum[tid] : 0.f;
        #pragma unroll
        for (int off = 1; off < NWF; off <<= 1) {
            float o = __shfl_up(sv, off);
            if (tid >= off) sv += o;
        }
        if (tid < NWF) wsum[tid] = sv;
    }
    __syncthreads();
    float cum = c + ((wv > 0) ? wsum[wv - 1] : 0.f);
    float excl = cum - p;                       // replicate (cumsum - p) rounding shape
    float p0 = __uint_as_float((unsigned)(cand[0] >> 32));
    float thrmp = p0 * minp;
    float p1v = (excl <= topp) ? p : 0.f;
    float v = (p1v >= thrmp) ? p1v : 0.f;
    __syncthreads();

    float cv = v;
    #pragma unroll
    for (int off = 1; off < 64; off <<= 1) {
        float o = __shfl_up(cv, off);
        if (lane >= off) cv += o;
    }
    if (lane == 63) wsum[wv] = cv;
    __syncthreads();
    if (tid < 64) {
        float sv = (tid < NWF) ? wsum[tid] : 0.f;
        #pragma unroll
        for (int off = 1; off < NWF; off <<= 1) {
            float o = __shfl_up(sv, off);
            if (tid >= off) sv += o;
        }
        if (tid < NWF) wsum[tid] = sv;
    }
    __syncthreads();
    float cdf = cv + ((wv > 0) ? wsum[wv - 1] : 0.f);
    float total = wsum[NWF - 1];
    float target = uu * total;

    bool hit = (tid < tk) && (cdf > target);
    u64 mk = __ballot(hit);
    if (lane == 0) wfirst[wv] = mk ? (unsigned)__builtin_ctzll(mk) : 0xFFFFFFFFu;
    __syncthreads();
    if (tid == 0) {
        int sel = -1;
        for (int w = 0; w < NWF; ++w)
            if (wfirst[w] != 0xFFFFFFFFu) { sel = w * 64 + (int)wfirst[w]; break; }
        if (sel < 0) sel = 0;
        out[b] = (int)~(unsigned)cand[sel];
    }
}

// ---------------- Fallback: monolithic single kernel (round-1, passed) ----------------
#define FNT 512
#define FNBINS 1024
#define FKMARGIN 1224
__global__ __launch_bounds__(FNT) void sampler_mono(
    const float* __restrict__ logits, const float* __restrict__ temps,
    const float* __restrict__ minps, const float* __restrict__ topps,
    const int* __restrict__ topks, const float* __restrict__ us,
    int* __restrict__ out, int V)
{
    const int row = blockIdx.x;
    const int tid = threadIdx.x;
    const float t = temps[row];
    __shared__ unsigned int hist[FNBINS];
    __shared__ u64 cand[CAND_MAX];
    __shared__ float red[FNT / 64];
    __shared__ float s_m, s_denom;
    __shared__ unsigned s_thr, s_cnt;
    for (int i = tid; i < FNBINS; i += FNT) hist[i] = 0u;
    if (tid == 0) s_cnt = 0u;
    const float* xrow = logits + (size_t)row * (size_t)V;
    const int n4 = V >> 2;
    const float4* x4 = (const float4*)xrow;
    float lmax = -INFINITY;
    for (int i = tid; i < n4; i += FNT) {
        float4 v = x4[i];
        lmax = fmaxf(lmax, fmaxf(fmaxf(v.x, v.y), fmaxf(v.z, v.w)));
    }
    for (int i = (n4 << 2) + tid; i < V; i += FNT) lmax = fmaxf(lmax, xrow[i]);
    for (int off = 32; off > 0; off >>= 1) lmax = fmaxf(lmax, __shfl_xor(lmax, off));
    if ((tid & 63) == 0) red[tid >> 6] = lmax;
    __syncthreads();
    if (tid == 0) {
        float r = red[0];
        for (int w = 1; w < FNT / 64; ++w) r = fmaxf(r, red[w]);
        s_m = r / t;
    }
    __syncthreads();
    const float m = s_m;
    float lsum = 0.f;
    for (int i = tid; i < n4; i += FNT) {
        float4 v = x4[i];
        float e0 = expf(v.x / t - m), e1 = expf(v.y / t - m);
        float e2 = expf(v.z / t - m), e3 = expf(v.w / t - m);
        lsum += e0; lsum += e1; lsum += e2; lsum += e3;
        atomicAdd(&hist[__float_as_uint(e0) >> 20], 1u);
        atomicAdd(&hist[__float_as_uint(e1) >> 20], 1u);
        atomicAdd(&hist[__float_as_uint(e2) >> 20], 1u);
        atomicAdd(&hist[__float_as_uint(e3) >> 20], 1u);
    }
    for (int i = (n4 << 2) + tid; i < V; i += FNT) {
        float e = expf(xrow[i] / t - m);
        lsum += e;
        atomicAdd(&hist[__float_as_uint(e) >> 20], 1u);
    }
    for (int off = 32; off > 0; off >>= 1) lsum += __shfl_xor(lsum, off);
    if ((tid & 63) == 0) red[tid >> 6] = lsum;
    __syncthreads();
    if (tid == 0) {
        float r = 0.f;
        for (int w = 0; w < FNT / 64; ++w) r += red[w];
        s_denom = r;
    }
    __syncthreads();
    const float denom = s_denom;
    if (tid < 64) {
        const int lane = tid;
        const int CH = FNBINS / 64;
        const int base = lane * CH;
        unsigned c = 0;
        #pragma unroll
        for (int j = 0; j < CH; ++j) c += hist[base + j];
        unsigned tsuf = c;
        #pragma unroll
        for (int off = 1; off < 64; off <<= 1) {
            unsigned o = __shfl_down(tsuf, off);
            if (lane + off < 64) tsuf += o;
        }
        unsigned long long mask = __ballot(tsuf >= (unsigned)FKMARGIN);
        int lstar = 63 - __builtin_clzll(mask);
        unsigned above = __shfl(tsuf, (lstar + 1) & 63);
        if (lstar == 63) above = 0u;
        if (lane == 0) {
            unsigned run = above;
            int thrbin = lstar * CH;
            for (int bb = lstar * CH + CH - 1; bb >= lstar * CH; --bb) {
                run += hist[bb];
                if (run >= (unsigned)FKMARGIN) { thrbin = bb; break; }
            }
            s_thr = (unsigned)thrbin << 20;
        }
    }
    __syncthreads();
    const unsigned thrkey = s_thr;
    for (int i = tid; i < n4; i += FNT) {
        float4 v = x4[i];
        float e[4] = { expf(v.x / t - m), expf(v.y / t - m),
                       expf(v.z / t - m), expf(v.w / t - m) };
        #pragma unroll
        for (int c = 0; c < 4; ++c) {
            unsigned eb = __float_as_uint(e[c]);
            if (eb >= thrkey) {
                float p = e[c] / denom;
                unsigned pos = atomicAdd(&s_cnt, 1u);
                if (pos < CAND_MAX)
                    cand[pos] = ((u64)__float_as_uint(p) << 32) | (unsigned)(~(unsigned)((i << 2) + c));
            }
        }
    }
    for (int i = (n4 << 2) + tid; i < V; i += FNT) {
        float e = expf(xrow[i] / t - m);
        if (__float_as_uint(e) >= thrkey) {
            float p = e / denom;
            unsigned pos = atomicAdd(&s_cnt, 1u);
            if (pos < CAND_MAX)
                cand[pos] = ((u64)__float_as_uint(p) << 32) | (unsigned)(~(unsigned)i);
        }
    }
    __syncthreads();
    int n = (int)s_cnt; if (n > CAND_MAX) n = CAND_MAX;
    int n2 = 1; while (n2 < n) n2 <<= 1;
    for (int i = n + tid; i < n2; i += FNT) cand[i] = 0ULL;
    __syncthreads();
    for (int k = 2; k <= n2; k <<= 1) {
        for (int j = k >> 1; j > 0; j >>= 1) {
            for (int i = tid; i < n2; i += FNT) {
                int ixj = i ^ j;
                if (ixj > i) {
                    u64 a = cand[i], bb = cand[ixj];
                    bool sw = ((i & k) == 0) ? (a < bb) : (a > bb);
                    if (sw) { cand[i] = bb; cand[ixj] = a; }
                }
            }
            __syncthreads();
        }
    }
    if (tid == 0) {
        const float topp = topps[row], minp = minps[row], uu = us[row];
        int tk = topks[row];
        if (tk > n) tk = n;
        float p0 = __uint_as_float((unsigned)(cand[0] >> 32));
        float thrmp = p0 * minp;
        float cum = 0.f, total = 0.f;
        for (int i = 0; i < tk; ++i) {
            float p = __uint_as_float((unsigned)(cand[i] >> 32));
            cum = cum + p;
            float excl = cum - p;
            float p1 = (excl <= topp) ? p : 0.f;
            float v = (p1 >= thrmp) ? p1 : 0.f;
            total += v;
        }
        float target = uu * total;
        float cdf = 0.f; int sel = -1;
        cum = 0.f;
        for (int i = 0; i < tk; ++i) {
            float p = __uint_as_float((unsigned)(cand[i] >> 32));
            cum = cum + p;
            float excl = cum - p;
            float p1 = (excl <= topp) ? p : 0.f;
            float v = (p1 >= thrmp) ? p1 : 0.f;
            cdf += v;
            if (cdf > target) { sel = i; break; }
        }
        if (sel < 0) sel = 0;
        out[row] = (int)~(unsigned)cand[sel];
    }
}

extern "C" void kernel_launch(void* const* d_in, const int* in_sizes, int n_in,
                              void* d_out, int out_size, void* d_ws, size_t ws_size,
                              hipStream_t stream) {
    const float* logits = (const float*)d_in[0];
    const float* temps  = (const float*)d_in[1];
    const float* minps  = (const float*)d_in[2];
    const float* topps  = (const float*)d_in[3];
    const int*   topks  = (const int*)d_in[4];
    const float* us     = (const float*)d_in[5];
    const int B = in_sizes[1];
    const int V = in_sizes[0] / B;
    int* outp = (int*)d_out;

    const int slen = (((V + S - 1) / S) + 3) & ~3;   // slice length, mult of 4

    size_t need = 0;
    const size_t off_cand = need; need += (size_t)B * CAND_MAX * sizeof(u64);
    const size_t off_pos  = need; need += (size_t)B * sizeof(unsigned);
    const size_t off_cnt  = need; need += (size_t)B * sizeof(unsigned);
    const size_t off_max  = need; need += (size_t)B * S * sizeof(float);
    const size_t off_sum  = need; need += (size_t)B * S * sizeof(float);

    if (ws_size < need) {
        sampler_mono<<<dim3(B), dim3(FNT), 0, stream>>>(
            logits, temps, minps, topps, topks, us, outp, V);
        return;
    }

    char* w = (char*)d_ws;
    u64*      gcand = (u64*)(w + off_cand);
    unsigned* gpos  = (unsigned*)(w + off_pos);
    unsigned* gcnt  = (unsigned*)(w + off_cnt);
    float*    gmax  = (float*)(w + off_max);
    float*    gsum  = (float*)(w + off_sum);

    // zero gpos+gcnt (contiguous, 2*B*4 bytes)
    {
        const int n16 = (int)((2 * (size_t)B * sizeof(unsigned)) / 16);
        k_zero<<<dim3(4), dim3(256), 0, stream>>>((uint4*)gpos, n16);
    }

    k_pass1<<<dim3(S, B), dim3(NT1), 0, stream>>>(
        logits, temps, gmax, gsum, gcand, gpos, gcnt, V, slen);
    k_finish<<<dim3(B), dim3(NTF), 0, stream>>>(
        logits, gcand, gcnt, gmax, gsum, temps, minps, topps, topks, us, outp, V);
}

// Round 13
// 34.998 us; speedup vs baseline: 2.6958x; 1.2586x over previous
//
#include <hip/hip_runtime.h>
#include <hip/hip_bf16.h>
#include <stdint.h>

typedef unsigned long long u64;

#define S 16            // slices per row
#define SEGCAP 256      // per-slice candidate segment (expect ~182, 5.5-sigma safe)
#define NBF 8192        // fine bins for counting sort (range [2,8))
#define KBASE 0xC0000000u   // fkey(2.0f)
#define FSHIFT 11
#define KSHIFT 19       // coarse 13-bit key (slow path)
#define CAND_MAX 4096   // = S * SEGCAP
#define OVF 1
#define NT1 256
#define NW1 (NT1 / 64)
#define NTF 1024
#define NWF (NTF / 64)

__device__ __forceinline__ unsigned fkey(float x) {
    unsigned u = __float_as_uint(x);
    return ((int)u < 0) ? ~u : (u | 0x80000000u);
}

// ---------------- K1: single sweep: max + raw exp-sum + speculative collect ----
// Writes per-slice: gmax, gsum, gcnt16 (plain stores), gcand segment (padded
// with sentinel 0) -> NO workspace pre-zeroing needed anywhere.
__global__ __launch_bounds__(NT1) void k_pass1(
    const float* __restrict__ logits, const float* __restrict__ temps,
    float* __restrict__ gmax, float* __restrict__ gsum,
    u64* __restrict__ gcand, unsigned* __restrict__ gcnt16, int V, int slen)
{
    const int s = blockIdx.x, b = blockIdx.y, tid = threadIdx.x;
    __shared__ u64 buf[SEGCAP];
    __shared__ float redm[NW1], reds[NW1];
    __shared__ unsigned s_cnt;
    if (tid == 0) s_cnt = 0u;
    __syncthreads();

    const float t = temps[b];
    const float invt = 1.0f / t;      // raw-sum path; denom rounding class accepted
    const float* xrow = logits + (size_t)b * (size_t)V;
    const int beg = s * slen, end = min(V, beg + slen);
    const float4* x4 = (const float4*)xrow;
    const int beg4 = beg >> 2, end4 = end >> 2;

    float lmax = -INFINITY, lsum = 0.f;
    for (int idx = beg4 + tid; idx < end4; idx += NT1) {
        float4 v = x4[idx];
        lmax = fmaxf(lmax, fmaxf(fmaxf(v.x, v.y), fmaxf(v.z, v.w)));
        lsum += expf(v.x * invt); lsum += expf(v.y * invt);
        lsum += expf(v.z * invt); lsum += expf(v.w * invt);
        const int i0 = idx << 2;
        if (v.x >= 2.0f) { unsigned p = atomicAdd(&s_cnt, 1u); if (p < SEGCAP) buf[p] = ((u64)__float_as_uint(v.x) << 32) | (unsigned)(i0    ); }
        if (v.y >= 2.0f) { unsigned p = atomicAdd(&s_cnt, 1u); if (p < SEGCAP) buf[p] = ((u64)__float_as_uint(v.y) << 32) | (unsigned)(i0 + 1); }
        if (v.z >= 2.0f) { unsigned p = atomicAdd(&s_cnt, 1u); if (p < SEGCAP) buf[p] = ((u64)__float_as_uint(v.z) << 32) | (unsigned)(i0 + 2); }
        if (v.w >= 2.0f) { unsigned p = atomicAdd(&s_cnt, 1u); if (p < SEGCAP) buf[p] = ((u64)__float_as_uint(v.w) << 32) | (unsigned)(i0 + 3); }
    }
    for (int i = max(beg, end4 << 2) + tid; i < end; i += NT1) {
        float x = xrow[i];
        lmax = fmaxf(lmax, x);
        lsum += expf(x * invt);
        if (x >= 2.0f) { unsigned p = atomicAdd(&s_cnt, 1u); if (p < SEGCAP) buf[p] = ((u64)__float_as_uint(x) << 32) | (unsigned)i; }
    }

    for (int off = 32; off > 0; off >>= 1) {
        lmax = fmaxf(lmax, __shfl_xor(lmax, off));
        lsum += __shfl_xor(lsum, off);
    }
    if ((tid & 63) == 0) { redm[tid >> 6] = lmax; reds[tid >> 6] = lsum; }
    __syncthreads();
    if (tid == 0) {
        float m = redm[0], sum = reds[0];
        for (int w = 1; w < NW1; ++w) { m = fmaxf(m, redm[w]); sum += reds[w]; }
        gmax[b * S + s] = m;
        gsum[b * S + s] = sum;            // raw sum of expf(x/t), no max shift
        gcnt16[b * S + s] = s_cnt;        // raw count (may exceed SEGCAP -> slow path)
    }
    __syncthreads();
    const unsigned cw = min(s_cnt, (unsigned)SEGCAP);
    u64* dst = gcand + (size_t)b * CAND_MAX + (size_t)s * SEGCAP;
    for (int i = tid; i < SEGCAP; i += NT1)
        dst[i] = (i < (int)cw) ? buf[i] : 0ULL;   // sentinel-pad the tail
}

// ---------------- K2: per-row finish: counting sort (fast) / rescan+bitonic (slow) ----
__global__ __launch_bounds__(NTF) void k_finish(
    const float* __restrict__ logits, const u64* __restrict__ gcand,
    const unsigned* __restrict__ gcnt16,
    const float* __restrict__ gmax, const float* __restrict__ gsum,
    const float* __restrict__ temps, const float* __restrict__ minps,
    const float* __restrict__ topps, const int* __restrict__ topks,
    const float* __restrict__ us, int* __restrict__ out, int V)
{
    const int b = blockIdx.x, tid = threadIdx.x;
    __shared__ u64 cand[CAND_MAX];
    __shared__ unsigned h[NBF + 1];
    __shared__ float wsum[NWF];
    __shared__ unsigned wfirst[NWF];
    __shared__ float s_m, s_den;
    __shared__ int s_thri;
    __shared__ unsigned s_cnt, s_n, s_tot;

    const float t = temps[b];
    const int tk0 = topks[b];
    const unsigned tk0u = (unsigned)tk0;

    // wave 0: row max + denom + total/overflow from slice partials
    if (tid < 64) {
        const int lane = tid;
        float v = (lane < S) ? gmax[b * S + lane] : -INFINITY;
        float vv = v;
        for (int off = 32; off > 0; off >>= 1) vv = fmaxf(vv, __shfl_xor(vv, off));
        const float m = vv / t;
        float d = (lane < S) ? gsum[b * S + lane] * expf(-m) : 0.f;
        for (int off = 32; off > 0; off >>= 1) d += __shfl_xor(d, off);
        unsigned cs = (lane < S) ? gcnt16[b * S + lane] : 0u;
        unsigned ov = (cs > (unsigned)SEGCAP) ? 1u : 0u;
        unsigned tot = cs;
        for (int off = 32; off > 0; off >>= 1) { tot += __shfl_xor(tot, off); ov |= __shfl_xor(ov, off); }
        if (lane == 0) { s_m = m; s_den = d; s_tot = tot | (ov ? 0x80000000u : 0u); }
    }
    for (int i = tid; i <= NBF; i += NTF) h[i] = 0u;
    if (tid == 0) { s_cnt = 0u; s_thri = -1; }
    __syncthreads();
    const float m = s_m, denom = s_den;
    const unsigned totw = s_tot;
    const bool fast = !(totw & 0x80000000u) && totw >= tk0u
                      && isfinite(denom) && denom > 0.f;

    int n;
    if (fast) {
        // ---- candidates -> registers (fixed 4/thread, sentinel-skip) + fine hist ----
        const u64* src = gcand + (size_t)b * CAND_MAX;
        u64 myc[CAND_MAX / NTF];
        int mykf[CAND_MAX / NTF];
        #pragma unroll
        for (int k = 0; k < CAND_MAX / NTF; ++k) {
            u64 w = src[tid + k * NTF];
            myc[k] = w; mykf[k] = -1;
            if (w != 0ULL) {
                unsigned fk = ((unsigned)(w >> 32)) | 0x80000000u;  // fkey (x>0)
                unsigned kf = (fk - KBASE) >> FSHIFT;
                if (kf > (unsigned)(NBF - 1)) kf = NBF - 1;
                mykf[k] = (int)kf;
                atomicAdd(&h[kf], 1u);
            }
        }
        __syncthreads();

        // ---- block suffix-scan over h[0..NBF): h[bin] <- count above bin ----
        const int lane = tid & 63, wv = tid >> 6;
        unsigned cnt8[8];
        const int b0 = tid * 8;
        unsigned L = 0;
        #pragma unroll
        for (int j = 0; j < 8; ++j) { cnt8[j] = h[b0 + j]; L += cnt8[j]; }
        unsigned tsuf = L;
        #pragma unroll
        for (int off = 1; off < 64; off <<= 1) {
            unsigned o = __shfl_down(tsuf, off);
            if (lane + off < 64) tsuf += o;
        }
        if (lane == 0) wfirst[wv] = tsuf;
        __syncthreads();
        if (tid < 64) {
            unsigned sv = (tid < NWF) ? wfirst[tid] : 0u;
            #pragma unroll
            for (int off = 1; off < NWF; off <<= 1) {
                unsigned o = __shfl_down(sv, off);
                if (tid + off < NWF) sv += o;
            }
            if (tid < NWF) wfirst[tid] = sv;   // inclusive suffix of wave sums
        }
        __syncthreads();
        unsigned above = tsuf - L + ((wv + 1 < NWF) ? wfirst[wv + 1] : 0u);
        unsigned run = above;
        int mythr = -1;
        #pragma unroll
        for (int j = 7; j >= 0; --j) {
            unsigned incl = run + cnt8[j];
            if (mythr < 0 && incl >= tk0u) mythr = b0 + j;
            h[b0 + j] = run;
            run = incl;
        }
        __syncthreads();
        if (mythr >= 0) atomicMax(&s_thri, mythr);
        __syncthreads();
        const int thrbin = s_thri;
        if ((thrbin >> 3) == tid) s_n = h[thrbin] + cnt8[thrbin & 7];
        __syncthreads();
        n = (int)s_n;

        // ---- scatter: p = exp(x/t - m)/denom, dest via per-bin atomic ----
        #pragma unroll
        for (int k = 0; k < CAND_MAX / NTF; ++k) {
            if (mykf[k] >= thrbin) {
                unsigned ub = (unsigned)(myc[k] >> 32);
                float x = __uint_as_float(ub);
                float p = expf(x / t - m) / denom;
                unsigned dest = atomicAdd(&h[mykf[k]], 1u);
                if (dest < (unsigned)CAND_MAX)
                    cand[dest] = ((u64)__float_as_uint(p) << 32) | (unsigned)(~(unsigned)myc[k]);
            }
        }
        __syncthreads();

        // ---- fixup: insertion-sort multi-element bins (desc by composite) ----
        for (int bb = thrbin + tid; bb < NBF; bb += NTF) {
            unsigned endo = h[bb];          // post-scatter = start + cnt
            unsigned starto = h[bb + 1];    // = start of bin bb
            if (endo > starto + 1 && starto < tk0u) {
                for (unsigned ii = starto + 1; ii < endo; ++ii) {
                    u64 key = cand[ii];
                    unsigned jj = ii;
                    while (jj > starto && cand[jj - 1] < key) { cand[jj] = cand[jj - 1]; --jj; }
                    cand[jj] = key;
                }
            }
        }
        __syncthreads();
    } else {
        // ---- slow path (adversarial only): full hist + denom + rescan + bitonic ----
        const int lane = tid & 63, wv = tid >> 6;
        const float* xrow = logits + (size_t)b * (size_t)V;
        const float4* x4 = (const float4*)xrow;
        const int n4 = V >> 2;
        float lsum = 0.f;
        for (int i = tid; i < n4; i += NTF) {
            float4 v = x4[i];
            lsum += expf(v.x / t - m); lsum += expf(v.y / t - m);
            lsum += expf(v.z / t - m); lsum += expf(v.w / t - m);
            atomicAdd(&h[fkey(v.x) >> KSHIFT], 1u);
            atomicAdd(&h[fkey(v.y) >> KSHIFT], 1u);
            atomicAdd(&h[fkey(v.z) >> KSHIFT], 1u);
            atomicAdd(&h[fkey(v.w) >> KSHIFT], 1u);
        }
        for (int i = (n4 << 2) + tid; i < V; i += NTF) {
            lsum += expf(xrow[i] / t - m);
            atomicAdd(&h[fkey(xrow[i]) >> KSHIFT], 1u);
        }
        for (int off = 32; off > 0; off >>= 1) lsum += __shfl_xor(lsum, off);
        if (lane == 0) wsum[wv] = lsum;
        __syncthreads();
        if (tid == 0) {
            float d = 0.f;
            for (int w = 0; w < NWF; ++w) d += wsum[w];
            s_den = d;
        }
        __syncthreads();
        const float den2 = s_den;
        if (tid < 64) {
            const unsigned needed = tk0u;
            const int CH = NBF / 64;
            const int base = tid * CH;
            unsigned c = 0;
            for (int j = 0; j < CH; ++j) c += h[base + j];
            unsigned tsuf = c;
            for (int off = 1; off < 64; off <<= 1) {
                unsigned o = __shfl_down(tsuf, off);
                if (tid + off < 64) tsuf += o;
            }
            u64 mask = __ballot(tsuf >= needed);
            int lstar = 63 - __builtin_clzll(mask);
            unsigned above = __shfl(tsuf, (lstar + 1) & 63);
            if (lstar == 63) above = 0u;
            if (tid == 0) {
                unsigned run = above;
                int thrb = lstar * CH;
                for (int bb2 = lstar * CH + CH - 1; bb2 >= lstar * CH; --bb2) {
                    run += h[bb2];
                    if (run >= needed) { thrb = bb2; break; }
                }
                s_thri = thrb;
            }
        }
        __syncthreads();
        const unsigned thr = (unsigned)s_thri << KSHIFT;
        for (int i = tid; i < n4; i += NTF) {
            float4 v = x4[i];
            const int i0 = i << 2;
            #pragma unroll
            for (int c = 0; c < 4; ++c) {
                float x = (c == 0) ? v.x : (c == 1) ? v.y : (c == 2) ? v.z : v.w;
                if (fkey(x) >= thr) {
                    float p = expf(x / t - m) / den2;
                    unsigned pos = atomicAdd(&s_cnt, 1u);
                    if (pos < CAND_MAX)
                        cand[pos] = ((u64)__float_as_uint(p) << 32) | (unsigned)(~(unsigned)(i0 + c));
                }
            }
        }
        for (int i = (n4 << 2) + tid; i < V; i += NTF) {
            float x = xrow[i];
            if (fkey(x) >= thr) {
                float p = expf(x / t - m) / den2;
                unsigned pos = atomicAdd(&s_cnt, 1u);
                if (pos < CAND_MAX)
                    cand[pos] = ((u64)__float_as_uint(p) << 32) | (unsigned)(~(unsigned)i);
            }
        }
        __syncthreads();
        n = (int)min(s_cnt, (unsigned)CAND_MAX);
        int n2 = 1; while (n2 < n) n2 <<= 1;
        for (int i = n + tid; i < n2; i += NTF) cand[i] = 0ULL;
        __syncthreads();
        for (int k = 2; k <= n2; k <<= 1) {
            for (int j = k >> 1; j > 0; j >>= 1) {
                for (int i = tid; i < n2; i += NTF) {
                    int ixj = i ^ j;
                    if (ixj > i) {
                        u64 a = cand[i], bb2 = cand[ixj];
                        bool sw = ((i & k) == 0) ? (a < bb2) : (a > bb2);
                        if (sw) { cand[i] = bb2; cand[ixj] = a; }
                    }
                }
                __syncthreads();
            }
        }
    }

    // ---- parallel epilogue: thread i owns sorted element i ----
    const int lane = tid & 63, wv = tid >> 6;
    const float topp = topps[b], minp = minps[b], uu = us[b];
    int tk = tk0;
    if (tk > n) tk = n;
    if (tk > NTF) tk = NTF;

    float p = 0.f;
    if (tid < tk) p = __uint_as_float((unsigned)(cand[tid] >> 32));

    float c = p;
    #pragma unroll
    for (int off = 1; off < 64; off <<= 1) {
        float o = __shfl_up(c, off);
        if (lane >= off) c += o;
    }
    if (lane == 63) wsum[wv] = c;
    __syncthreads();
    if (tid < 64) {
        float sv = (tid < NWF) ? wsum[tid] : 0.f;
        #pragma unroll
        for (int off = 1; off < NWF; off <<= 1) {
            float o = __shfl_up(sv, off);
            if (tid >= off) sv += o;
        }
        if (tid < NWF) wsum[tid] = sv;
    }
    __syncthreads();
    float cum = c + ((wv > 0) ? wsum[wv - 1] : 0.f);
    float excl = cum - p;                       // replicate (cumsum - p) rounding shape
    float p0 = __uint_as_float((unsigned)(cand[0] >> 32));
    float thrmp = p0 * minp;
    float p1v = (excl <= topp) ? p : 0.f;
    float v = (p1v >= thrmp) ? p1v : 0.f;
    __syncthreads();

    float cv = v;
    #pragma unroll
    for (int off = 1; off < 64; off <<= 1) {
        float o = __shfl_up(cv, off);
        if (lane >= off) cv += o;
    }
    if (lane == 63) wsum[wv] = cv;
    __syncthreads();
    if (tid < 64) {
        float sv = (tid < NWF) ? wsum[tid] : 0.f;
        #pragma unroll
        for (int off = 1; off < NWF; off <<= 1) {
            float o = __shfl_up(sv, off);
            if (tid >= off) sv += o;
        }
        if (tid < NWF) wsum[tid] = sv;
    }
    __syncthreads();
    float cdf = cv + ((wv > 0) ? wsum[wv - 1] : 0.f);
    float total = wsum[NWF - 1];
    float target = uu * total;

    bool hit = (tid < tk) && (cdf > target);
    u64 mk = __ballot(hit);
    if (lane == 0) wfirst[wv] = mk ? (unsigned)__builtin_ctzll(mk) : 0xFFFFFFFFu;
    __syncthreads();
    if (tid == 0) {
        int sel = -1;
        for (int w = 0; w < NWF; ++w)
            if (wfirst[w] != 0xFFFFFFFFu) { sel = w * 64 + (int)wfirst[w]; break; }
        if (sel < 0) sel = 0;
        out[b] = (int)~(unsigned)cand[sel];
    }
}

// ---------------- Fallback: monolithic single kernel (round-1, passed) ----------------
#define FNT 512
#define FNBINS 1024
#define FKMARGIN 1224
__global__ __launch_bounds__(FNT) void sampler_mono(
    const float* __restrict__ logits, const float* __restrict__ temps,
    const float* __restrict__ minps, const float* __restrict__ topps,
    const int* __restrict__ topks, const float* __restrict__ us,
    int* __restrict__ out, int V)
{
    const int row = blockIdx.x;
    const int tid = threadIdx.x;
    const float t = temps[row];
    __shared__ unsigned int hist[FNBINS];
    __shared__ u64 cand[CAND_MAX];
    __shared__ float red[FNT / 64];
    __shared__ float s_m, s_denom;
    __shared__ unsigned s_thr, s_cnt;
    for (int i = tid; i < FNBINS; i += FNT) hist[i] = 0u;
    if (tid == 0) s_cnt = 0u;
    const float* xrow = logits + (size_t)row * (size_t)V;
    const int n4 = V >> 2;
    const float4* x4 = (const float4*)xrow;
    float lmax = -INFINITY;
    for (int i = tid; i < n4; i += FNT) {
        float4 v = x4[i];
        lmax = fmaxf(lmax, fmaxf(fmaxf(v.x, v.y), fmaxf(v.z, v.w)));
    }
    for (int i = (n4 << 2) + tid; i < V; i += FNT) lmax = fmaxf(lmax, xrow[i]);
    for (int off = 32; off > 0; off >>= 1) lmax = fmaxf(lmax, __shfl_xor(lmax, off));
    if ((tid & 63) == 0) red[tid >> 6] = lmax;
    __syncthreads();
    if (tid == 0) {
        float r = red[0];
        for (int w = 1; w < FNT / 64; ++w) r = fmaxf(r, red[w]);
        s_m = r / t;
    }
    __syncthreads();
    const float m = s_m;
    float lsum = 0.f;
    for (int i = tid; i < n4; i += FNT) {
        float4 v = x4[i];
        float e0 = expf(v.x / t - m), e1 = expf(v.y / t - m);
        float e2 = expf(v.z / t - m), e3 = expf(v.w / t - m);
        lsum += e0; lsum += e1; lsum += e2; lsum += e3;
        atomicAdd(&hist[__float_as_uint(e0) >> 20], 1u);
        atomicAdd(&hist[__float_as_uint(e1) >> 20], 1u);
        atomicAdd(&hist[__float_as_uint(e2) >> 20], 1u);
        atomicAdd(&hist[__float_as_uint(e3) >> 20], 1u);
    }
    for (int i = (n4 << 2) + tid; i < V; i += FNT) {
        float e = expf(xrow[i] / t - m);
        lsum += e;
        atomicAdd(&hist[__float_as_uint(e) >> 20], 1u);
    }
    for (int off = 32; off > 0; off >>= 1) lsum += __shfl_xor(lsum, off);
    if ((tid & 63) == 0) red[tid >> 6] = lsum;
    __syncthreads();
    if (tid == 0) {
        float r = 0.f;
        for (int w = 0; w < FNT / 64; ++w) r += red[w];
        s_denom = r;
    }
    __syncthreads();
    const float denom = s_denom;
    if (tid < 64) {
        const int lane = tid;
        const int CH = FNBINS / 64;
        const int base = lane * CH;
        unsigned c = 0;
        #pragma unroll
        for (int j = 0; j < CH; ++j) c += hist[base + j];
        unsigned tsuf = c;
        #pragma unroll
        for (int off = 1; off < 64; off <<= 1) {
            unsigned o = __shfl_down(tsuf, off);
            if (lane + off < 64) tsuf += o;
        }
        unsigned long long mask = __ballot(tsuf >= (unsigned)FKMARGIN);
        int lstar = 63 - __builtin_clzll(mask);
        unsigned above = __shfl(tsuf, (lstar + 1) & 63);
        if (lstar == 63) above = 0u;
        if (lane == 0) {
            unsigned run = above;
            int thrbin = lstar * CH;
            for (int bb = lstar * CH + CH - 1; bb >= lstar * CH; --bb) {
                run += hist[bb];
                if (run >= (unsigned)FKMARGIN) { thrbin = bb; break; }
            }
            s_thr = (unsigned)thrbin << 20;
        }
    }
    __syncthreads();
    const unsigned thrkey = s_thr;
    for (int i = tid; i < n4; i += FNT) {
        float4 v = x4[i];
        float e[4] = { expf(v.x / t - m), expf(v.y / t - m),
                       expf(v.z / t - m), expf(v.w / t - m) };
        #pragma unroll
        for (int c = 0; c < 4; ++c) {
            unsigned eb = __float_as_uint(e[c]);
            if (eb >= thrkey) {
                float p = e[c] / denom;
                unsigned pos = atomicAdd(&s_cnt, 1u);
                if (pos < CAND_MAX)
                    cand[pos] = ((u64)__float_as_uint(p) << 32) | (unsigned)(~(unsigned)((i << 2) + c));
            }
        }
    }
    for (int i = (n4 << 2) + tid; i < V; i += FNT) {
        float e = expf(xrow[i] / t - m);
        if (__float_as_uint(e) >= thrkey) {
            float p = e / denom;
            unsigned pos = atomicAdd(&s_cnt, 1u);
            if (pos < CAND_MAX)
                cand[pos] = ((u64)__float_as_uint(p) << 32) | (unsigned)(~(unsigned)i);
        }
    }
    __syncthreads();
    int n = (int)s_cnt; if (n > CAND_MAX) n = CAND_MAX;
    int n2 = 1; while (n2 < n) n2 <<= 1;
    for (int i = n + tid; i < n2; i += FNT) cand[i] = 0ULL;
    __syncthreads();
    for (int k = 2; k <= n2; k <<= 1) {
        for (int j = k >> 1; j > 0; j >>= 1) {
            for (int i = tid; i < n2; i += FNT) {
                int ixj = i ^ j;
                if (ixj > i) {
                    u64 a = cand[i], bb = cand[ixj];
                    bool sw = ((i & k) == 0) ? (a < bb) : (a > bb);
                    if (sw) { cand[i] = bb; cand[ixj] = a; }
                }
            }
            __syncthreads();
        }
    }
    if (tid == 0) {
        const float topp = topps[row], minp = minps[row], uu = us[row];
        int tk = topks[row];
        if (tk > n) tk = n;
        float p0 = __uint_as_float((unsigned)(cand[0] >> 32));
        float thrmp = p0 * minp;
        float cum = 0.f, total = 0.f;
        for (int i = 0; i < tk; ++i) {
            float p = __uint_as_float((unsigned)(cand[i] >> 32));
            cum = cum + p;
            float excl = cum - p;
            float p1 = (excl <= topp) ? p : 0.f;
            float v = (p1 >= thrmp) ? p1 : 0.f;
            total += v;
        }
        float target = uu * total;
        float cdf = 0.f; int sel = -1;
        cum = 0.f;
        for (int i = 0; i < tk; ++i) {
            float p = __uint_as_float((unsigned)(cand[i] >> 32));
            cum = cum + p;
            float excl = cum - p;
            float p1 = (excl <= topp) ? p : 0.f;
            float v = (p1 >= thrmp) ? p1 : 0.f;
            cdf += v;
            if (cdf > target) { sel = i; break; }
        }
        if (sel < 0) sel = 0;
        out[row] = (int)~(unsigned)cand[sel];
    }
}

extern "C" void kernel_launch(void* const* d_in, const int* in_sizes, int n_in,
                              void* d_out, int out_size, void* d_ws, size_t ws_size,
                              hipStream_t stream) {
    const float* logits = (const float*)d_in[0];
    const float* temps  = (const float*)d_in[1];
    const float* minps  = (const float*)d_in[2];
    const float* topps  = (const float*)d_in[3];
    const int*   topks  = (const int*)d_in[4];
    const float* us     = (const float*)d_in[5];
    const int B = in_sizes[1];
    const int V = in_sizes[0] / B;
    int* outp = (int*)d_out;

    const int slen = (((V + S - 1) / S) + 3) & ~3;   // slice length, mult of 4

    size_t need = 0;
    const size_t off_cand = need; need += (size_t)B * CAND_MAX * sizeof(u64);
    const size_t off_cnt  = need; need += (size_t)B * S * sizeof(unsigned);
    const size_t off_max  = need; need += (size_t)B * S * sizeof(float);
    const size_t off_sum  = need; need += (size_t)B * S * sizeof(float);

    if (ws_size < need) {
        sampler_mono<<<dim3(B), dim3(FNT), 0, stream>>>(
            logits, temps, minps, topps, topks, us, outp, V);
        return;
    }

    char* w = (char*)d_ws;
    u64*      gcand  = (u64*)(w + off_cand);
    unsigned* gcnt16 = (unsigned*)(w + off_cnt);
    float*    gmax   = (float*)(w + off_max);
    float*    gsum   = (float*)(w + off_sum);

    // No workspace zeroing needed: every word read is written this call.
    k_pass1<<<dim3(S, B), dim3(NT1), 0, stream>>>(
        logits, temps, gmax, gsum, gcand, gcnt16, V, slen);
    k_finish<<<dim3(B), dim3(NTF), 0, stream>>>(
        logits, gcand, gcnt16, gmax, gsum, temps, minps, topps, topks, us, outp, V);
}

// Round 14
// 32.322 us; speedup vs baseline: 2.9190x; 1.0828x over previous
//
#include <hip/hip_runtime.h>
#include <hip/hip_bf16.h>
#include <stdint.h>

typedef unsigned long long u64;

#define S 16            // slices per row
#define SEGCAP 256      // per-slice candidate segment (expect ~182, 5.5-sigma safe)
#define NBF 8192        // fine bins for counting sort (range [2,8))
#define KBASE 0xC0000000u   // fkey(2.0f)
#define FSHIFT 11
#define KSHIFT 19       // coarse 13-bit key (slow path)
#define CAND_MAX 4096   // = S * SEGCAP
#define NT1 256
#define NW1 (NT1 / 64)
#define NTF 1024
#define NWF (NTF / 64)

__device__ __forceinline__ unsigned fkey(float x) {
    unsigned u = __float_as_uint(x);
    return ((int)u < 0) ? ~u : (u | 0x80000000u);
}

// ---------------- K1: single sweep: max + raw exp-sum + speculative collect ----
// 2-wide unrolled, dual accumulator chains, native exp. Writes per-slice:
// gmax, gsum, gcnt16, gcand segment (sentinel-0 padded) -> no pre-zeroing.
__global__ __launch_bounds__(NT1) void k_pass1(
    const float* __restrict__ logits, const float* __restrict__ temps,
    float* __restrict__ gmax, float* __restrict__ gsum,
    u64* __restrict__ gcand, unsigned* __restrict__ gcnt16, int V, int slen)
{
    const int s = blockIdx.x, b = blockIdx.y, tid = threadIdx.x;
    __shared__ u64 buf[SEGCAP];
    __shared__ float redm[NW1], reds[NW1];
    __shared__ unsigned s_cnt;
    if (tid == 0) s_cnt = 0u;
    __syncthreads();

    const float t = temps[b];
    const float invt = 1.0f / t;      // denom-only rounding class (accepted)
    const float* xrow = logits + (size_t)b * (size_t)V;
    const int beg = s * slen, end = min(V, beg + slen);
    const float4* x4 = (const float4*)xrow;
    const int beg4 = beg >> 2, end4 = end >> 2;

    float lmax0 = -INFINITY, lmax1 = -INFINITY;
    float lsum0 = 0.f, lsum1 = 0.f;
    const float4 pad = make_float4(-INFINITY, -INFINITY, -INFINITY, -INFINITY);

    for (int idx = beg4 + tid; idx < end4; idx += 2 * NT1) {
        float4 a = x4[idx];
        const int jb = idx + NT1;
        float4 bv = (jb < end4) ? x4[jb] : pad;    // expf(-inf)=0, fmax neutral

        lmax0 = fmaxf(lmax0, fmaxf(fmaxf(a.x, a.y), fmaxf(a.z, a.w)));
        lmax1 = fmaxf(lmax1, fmaxf(fmaxf(bv.x, bv.y), fmaxf(bv.z, bv.w)));
        lsum0 += __expf(a.x * invt);  lsum0 += __expf(a.y * invt);
        lsum0 += __expf(a.z * invt);  lsum0 += __expf(a.w * invt);
        lsum1 += __expf(bv.x * invt); lsum1 += __expf(bv.y * invt);
        lsum1 += __expf(bv.z * invt); lsum1 += __expf(bv.w * invt);

        const int i0 = idx << 2;
        if (a.x >= 2.0f) { unsigned p = atomicAdd(&s_cnt, 1u); if (p < SEGCAP) buf[p] = ((u64)__float_as_uint(a.x) << 32) | (unsigned)(i0    ); }
        if (a.y >= 2.0f) { unsigned p = atomicAdd(&s_cnt, 1u); if (p < SEGCAP) buf[p] = ((u64)__float_as_uint(a.y) << 32) | (unsigned)(i0 + 1); }
        if (a.z >= 2.0f) { unsigned p = atomicAdd(&s_cnt, 1u); if (p < SEGCAP) buf[p] = ((u64)__float_as_uint(a.z) << 32) | (unsigned)(i0 + 2); }
        if (a.w >= 2.0f) { unsigned p = atomicAdd(&s_cnt, 1u); if (p < SEGCAP) buf[p] = ((u64)__float_as_uint(a.w) << 32) | (unsigned)(i0 + 3); }
        const int i1 = jb << 2;
        if (bv.x >= 2.0f) { unsigned p = atomicAdd(&s_cnt, 1u); if (p < SEGCAP) buf[p] = ((u64)__float_as_uint(bv.x) << 32) | (unsigned)(i1    ); }
        if (bv.y >= 2.0f) { unsigned p = atomicAdd(&s_cnt, 1u); if (p < SEGCAP) buf[p] = ((u64)__float_as_uint(bv.y) << 32) | (unsigned)(i1 + 1); }
        if (bv.z >= 2.0f) { unsigned p = atomicAdd(&s_cnt, 1u); if (p < SEGCAP) buf[p] = ((u64)__float_as_uint(bv.z) << 32) | (unsigned)(i1 + 2); }
        if (bv.w >= 2.0f) { unsigned p = atomicAdd(&s_cnt, 1u); if (p < SEGCAP) buf[p] = ((u64)__float_as_uint(bv.w) << 32) | (unsigned)(i1 + 3); }
    }
    for (int i = max(beg, end4 << 2) + tid; i < end; i += NT1) {
        float x = xrow[i];
        lmax0 = fmaxf(lmax0, x);
        lsum0 += __expf(x * invt);
        if (x >= 2.0f) { unsigned p = atomicAdd(&s_cnt, 1u); if (p < SEGCAP) buf[p] = ((u64)__float_as_uint(x) << 32) | (unsigned)i; }
    }

    float lmax = fmaxf(lmax0, lmax1);
    float lsum = lsum0 + lsum1;
    for (int off = 32; off > 0; off >>= 1) {
        lmax = fmaxf(lmax, __shfl_xor(lmax, off));
        lsum += __shfl_xor(lsum, off);
    }
    if ((tid & 63) == 0) { redm[tid >> 6] = lmax; reds[tid >> 6] = lsum; }
    __syncthreads();
    if (tid == 0) {
        float m = redm[0], sum = reds[0];
        for (int w = 1; w < NW1; ++w) { m = fmaxf(m, redm[w]); sum += reds[w]; }
        gmax[b * S + s] = m;
        gsum[b * S + s] = sum;            // raw sum of exp(x/t), no max shift
        gcnt16[b * S + s] = s_cnt;        // raw count (> SEGCAP -> slow path)
    }
    __syncthreads();
    const unsigned cw = min(s_cnt, (unsigned)SEGCAP);
    u64* dst = gcand + (size_t)b * CAND_MAX + (size_t)s * SEGCAP;
    for (int i = tid; i < SEGCAP; i += NT1)
        dst[i] = (i < (int)cw) ? buf[i] : 0ULL;   // sentinel-pad the tail
}

// ---------------- K2: per-row finish: counting sort (fast) / rescan+bitonic (slow) ----
__global__ __launch_bounds__(NTF) void k_finish(
    const float* __restrict__ logits, const u64* __restrict__ gcand,
    const unsigned* __restrict__ gcnt16,
    const float* __restrict__ gmax, const float* __restrict__ gsum,
    const float* __restrict__ temps, const float* __restrict__ minps,
    const float* __restrict__ topps, const int* __restrict__ topks,
    const float* __restrict__ us, int* __restrict__ out, int V)
{
    const int b = blockIdx.x, tid = threadIdx.x;
    __shared__ u64 cand[CAND_MAX];
    __shared__ unsigned h[NBF + 1];
    __shared__ float wsum[NWF];
    __shared__ unsigned wfirst[NWF];
    __shared__ float s_m, s_den;
    __shared__ int s_thri;
    __shared__ unsigned s_cnt, s_n, s_tot;

    const float t = temps[b];
    const int tk0 = topks[b];
    const unsigned tk0u = (unsigned)tk0;

    // wave 0: row max (slow path only) + raw denom + total/overflow
    if (tid < 64) {
        const int lane = tid;
        float v = (lane < S) ? gmax[b * S + lane] : -INFINITY;
        float vv = v;
        for (int off = 32; off > 0; off >>= 1) vv = fmaxf(vv, __shfl_xor(vv, off));
        const float m = vv / t;
        float d = (lane < S) ? gsum[b * S + lane] : 0.f;    // raw, no e^{-m}
        for (int off = 32; off > 0; off >>= 1) d += __shfl_xor(d, off);
        unsigned cs = (lane < S) ? gcnt16[b * S + lane] : 0u;
        unsigned ov = (cs > (unsigned)SEGCAP) ? 1u : 0u;
        unsigned tot = cs;
        for (int off = 32; off > 0; off >>= 1) { tot += __shfl_xor(tot, off); ov |= __shfl_xor(ov, off); }
        if (lane == 0) { s_m = m; s_den = d; s_tot = tot | (ov ? 0x80000000u : 0u); }
    }
    for (int i = tid; i <= NBF; i += NTF) h[i] = 0u;
    if (tid == 0) { s_cnt = 0u; s_thri = -1; }
    __syncthreads();
    const float m = s_m, denom = s_den;
    const unsigned totw = s_tot;
    const bool fast = !(totw & 0x80000000u) && totw >= tk0u
                      && isfinite(denom) && denom > 0.f;

    int n;
    if (fast) {
        // ---- candidates -> registers (fixed 4/thread, sentinel-skip) + fine hist ----
        const u64* src = gcand + (size_t)b * CAND_MAX;
        u64 myc[CAND_MAX / NTF];
        int mykf[CAND_MAX / NTF];
        #pragma unroll
        for (int k = 0; k < CAND_MAX / NTF; ++k) {
            u64 w = src[tid + k * NTF];
            myc[k] = w; mykf[k] = -1;
            if (w != 0ULL) {
                unsigned fk = ((unsigned)(w >> 32)) | 0x80000000u;  // fkey (x>0)
                unsigned kf = (fk - KBASE) >> FSHIFT;
                if (kf > (unsigned)(NBF - 1)) kf = NBF - 1;
                mykf[k] = (int)kf;
                atomicAdd(&h[kf], 1u);
            }
        }
        __syncthreads();

        // ---- block suffix-scan over h[0..NBF): h[bin] <- count above bin ----
        const int lane = tid & 63, wv = tid >> 6;
        unsigned cnt8[8];
        const int b0 = tid * 8;
        unsigned L = 0;
        #pragma unroll
        for (int j = 0; j < 8; ++j) { cnt8[j] = h[b0 + j]; L += cnt8[j]; }
        unsigned tsuf = L;
        #pragma unroll
        for (int off = 1; off < 64; off <<= 1) {
            unsigned o = __shfl_down(tsuf, off);
            if (lane + off < 64) tsuf += o;
        }
        if (lane == 0) wfirst[wv] = tsuf;
        __syncthreads();
        if (tid < 64) {
            unsigned sv = (tid < NWF) ? wfirst[tid] : 0u;
            #pragma unroll
            for (int off = 1; off < NWF; off <<= 1) {
                unsigned o = __shfl_down(sv, off);
                if (tid + off < NWF) sv += o;
            }
            if (tid < NWF) wfirst[tid] = sv;   // inclusive suffix of wave sums
        }
        __syncthreads();
        unsigned above = tsuf - L + ((wv + 1 < NWF) ? wfirst[wv + 1] : 0u);
        unsigned run = above;
        int mythr = -1;
        #pragma unroll
        for (int j = 7; j >= 0; --j) {
            unsigned incl = run + cnt8[j];
            if (mythr < 0 && incl >= tk0u) mythr = b0 + j;
            h[b0 + j] = run;
            run = incl;
        }
        __syncthreads();
        if (mythr >= 0) atomicMax(&s_thri, mythr);
        __syncthreads();
        const int thrbin = s_thri;
        if ((thrbin >> 3) == tid) s_n = h[thrbin] + cnt8[thrbin & 7];
        __syncthreads();
        n = (int)s_n;

        // ---- scatter: p = exp(x/t)/denom (raw, no shift), dest via per-bin atomic ----
        #pragma unroll
        for (int k = 0; k < CAND_MAX / NTF; ++k) {
            if (mykf[k] >= thrbin) {
                unsigned ub = (unsigned)(myc[k] >> 32);
                float x = __uint_as_float(ub);
                float p = expf(x / t) / denom;
                unsigned dest = atomicAdd(&h[mykf[k]], 1u);
                if (dest < (unsigned)CAND_MAX)
                    cand[dest] = ((u64)__float_as_uint(p) << 32) | (unsigned)(~(unsigned)myc[k]);
            }
        }
        __syncthreads();

        // ---- fixup: insertion-sort multi-element bins (desc by composite) ----
        for (int bb = thrbin + tid; bb < NBF; bb += NTF) {
            unsigned endo = h[bb];          // post-scatter = start + cnt
            unsigned starto = h[bb + 1];    // = start of bin bb
            if (endo > starto + 1 && starto < tk0u) {
                for (unsigned ii = starto + 1; ii < endo; ++ii) {
                    u64 key = cand[ii];
                    unsigned jj = ii;
                    while (jj > starto && cand[jj - 1] < key) { cand[jj] = cand[jj - 1]; --jj; }
                    cand[jj] = key;
                }
            }
        }
        __syncthreads();
    } else {
        // ---- slow path (adversarial only): full hist + denom + rescan + bitonic ----
        const int lane = tid & 63, wv = tid >> 6;
        const float* xrow = logits + (size_t)b * (size_t)V;
        const float4* x4 = (const float4*)xrow;
        const int n4 = V >> 2;
        float lsum = 0.f;
        for (int i = tid; i < n4; i += NTF) {
            float4 v = x4[i];
            lsum += expf(v.x / t - m); lsum += expf(v.y / t - m);
            lsum += expf(v.z / t - m); lsum += expf(v.w / t - m);
            atomicAdd(&h[fkey(v.x) >> KSHIFT], 1u);
            atomicAdd(&h[fkey(v.y) >> KSHIFT], 1u);
            atomicAdd(&h[fkey(v.z) >> KSHIFT], 1u);
            atomicAdd(&h[fkey(v.w) >> KSHIFT], 1u);
        }
        for (int i = (n4 << 2) + tid; i < V; i += NTF) {
            lsum += expf(xrow[i] / t - m);
            atomicAdd(&h[fkey(xrow[i]) >> KSHIFT], 1u);
        }
        for (int off = 32; off > 0; off >>= 1) lsum += __shfl_xor(lsum, off);
        if (lane == 0) wsum[wv] = lsum;
        __syncthreads();
        if (tid == 0) {
            float d = 0.f;
            for (int w = 0; w < NWF; ++w) d += wsum[w];
            s_den = d;
        }
        __syncthreads();
        const float den2 = s_den;
        if (tid < 64) {
            const unsigned needed = tk0u;
            const int CH = NBF / 64;
            const int base = tid * CH;
            unsigned c = 0;
            for (int j = 0; j < CH; ++j) c += h[base + j];
            unsigned tsuf = c;
            for (int off = 1; off < 64; off <<= 1) {
                unsigned o = __shfl_down(tsuf, off);
                if (tid + off < 64) tsuf += o;
            }
            u64 mask = __ballot(tsuf >= needed);
            int lstar = 63 - __builtin_clzll(mask);
            unsigned above = __shfl(tsuf, (lstar + 1) & 63);
            if (lstar == 63) above = 0u;
            if (tid == 0) {
                unsigned run = above;
                int thrb = lstar * CH;
                for (int bb2 = lstar * CH + CH - 1; bb2 >= lstar * CH; --bb2) {
                    run += h[bb2];
                    if (run >= needed) { thrb = bb2; break; }
                }
                s_thri = thrb;
            }
        }
        __syncthreads();
        const unsigned thr = (unsigned)s_thri << KSHIFT;
        for (int i = tid; i < n4; i += NTF) {
            float4 v = x4[i];
            const int i0 = i << 2;
            #pragma unroll
            for (int c = 0; c < 4; ++c) {
                float x = (c == 0) ? v.x : (c == 1) ? v.y : (c == 2) ? v.z : v.w;
                if (fkey(x) >= thr) {
                    float p = expf(x / t - m) / den2;
                    unsigned pos = atomicAdd(&s_cnt, 1u);
                    if (pos < CAND_MAX)
                        cand[pos] = ((u64)__float_as_uint(p) << 32) | (unsigned)(~(unsigned)(i0 + c));
                }
            }
        }
        for (int i = (n4 << 2) + tid; i < V; i += NTF) {
            float x = xrow[i];
            if (fkey(x) >= thr) {
                float p = expf(x / t - m) / den2;
                unsigned pos = atomicAdd(&s_cnt, 1u);
                if (pos < CAND_MAX)
                    cand[pos] = ((u64)__float_as_uint(p) << 32) | (unsigned)(~(unsigned)i);
            }
        }
        __syncthreads();
        n = (int)min(s_cnt, (unsigned)CAND_MAX);
        int n2 = 1; while (n2 < n) n2 <<= 1;
        for (int i = n + tid; i < n2; i += NTF) cand[i] = 0ULL;
        __syncthreads();
        for (int k = 2; k <= n2; k <<= 1) {
            for (int j = k >> 1; j > 0; j >>= 1) {
                for (int i = tid; i < n2; i += NTF) {
                    int ixj = i ^ j;
                    if (ixj > i) {
                        u64 a = cand[i], bb2 = cand[ixj];
                        bool sw = ((i & k) == 0) ? (a < bb2) : (a > bb2);
                        if (sw) { cand[i] = bb2; cand[ixj] = a; }
                    }
                }
                __syncthreads();
            }
        }
    }

    // ---- parallel epilogue: thread i owns sorted element i ----
    const int lane = tid & 63, wv = tid >> 6;
    const float topp = topps[b], minp = minps[b], uu = us[b];
    int tk = tk0;
    if (tk > n) tk = n;
    if (tk > NTF) tk = NTF;

    float p = 0.f;
    if (tid < tk) p = __uint_as_float((unsigned)(cand[tid] >> 32));

    float c = p;
    #pragma unroll
    for (int off = 1; off < 64; off <<= 1) {
        float o = __shfl_up(c, off);
        if (lane >= off) c += o;
    }
    if (lane == 63) wsum[wv] = c;
    __syncthreads();
    if (tid < 64) {
        float sv = (tid < NWF) ? wsum[tid] : 0.f;
        #pragma unroll
        for (int off = 1; off < NWF; off <<= 1) {
            float o = __shfl_up(sv, off);
            if (tid >= off) sv += o;
        }
        if (tid < NWF) wsum[tid] = sv;
    }
    __syncthreads();
    float cum = c + ((wv > 0) ? wsum[wv - 1] : 0.f);
    float excl = cum - p;                       // replicate (cumsum - p) rounding shape
    float p0 = __uint_as_float((unsigned)(cand[0] >> 32));
    float thrmp = p0 * minp;
    float p1v = (excl <= topp) ? p : 0.f;
    float v = (p1v >= thrmp) ? p1v : 0.f;
    __syncthreads();

    float cv = v;
    #pragma unroll
    for (int off = 1; off < 64; off <<= 1) {
        float o = __shfl_up(cv, off);
        if (lane >= off) cv += o;
    }
    if (lane == 63) wsum[wv] = cv;
    __syncthreads();
    if (tid < 64) {
        float sv = (tid < NWF) ? wsum[tid] : 0.f;
        #pragma unroll
        for (int off = 1; off < NWF; off <<= 1) {
            float o = __shfl_up(sv, off);
            if (tid >= off) sv += o;
        }
        if (tid < NWF) wsum[tid] = sv;
    }
    __syncthreads();
    float cdf = cv + ((wv > 0) ? wsum[wv - 1] : 0.f);
    float total = wsum[NWF - 1];
    float target = uu * total;

    bool hit = (tid < tk) && (cdf > target);
    u64 mk = __ballot(hit);
    if (lane == 0) wfirst[wv] = mk ? (unsigned)__builtin_ctzll(mk) : 0xFFFFFFFFu;
    __syncthreads();
    if (tid == 0) {
        int sel = -1;
        for (int w = 0; w < NWF; ++w)
            if (wfirst[w] != 0xFFFFFFFFu) { sel = w * 64 + (int)wfirst[w]; break; }
        if (sel < 0) sel = 0;
        out[b] = (int)~(unsigned)cand[sel];
    }
}

// ---------------- Fallback: monolithic single kernel (round-1, passed) ----------------
#define FNT 512
#define FNBINS 1024
#define FKMARGIN 1224
__global__ __launch_bounds__(FNT) void sampler_mono(
    const float* __restrict__ logits, const float* __restrict__ temps,
    const float* __restrict__ minps, const float* __restrict__ topps,
    const int* __restrict__ topks, const float* __restrict__ us,
    int* __restrict__ out, int V)
{
    const int row = blockIdx.x;
    const int tid = threadIdx.x;
    const float t = temps[row];
    __shared__ unsigned int hist[FNBINS];
    __shared__ u64 cand[CAND_MAX];
    __shared__ float red[FNT / 64];
    __shared__ float s_m, s_denom;
    __shared__ unsigned s_thr, s_cnt;
    for (int i = tid; i < FNBINS; i += FNT) hist[i] = 0u;
    if (tid == 0) s_cnt = 0u;
    const float* xrow = logits + (size_t)row * (size_t)V;
    const int n4 = V >> 2;
    const float4* x4 = (const float4*)xrow;
    float lmax = -INFINITY;
    for (int i = tid; i < n4; i += FNT) {
        float4 v = x4[i];
        lmax = fmaxf(lmax, fmaxf(fmaxf(v.x, v.y), fmaxf(v.z, v.w)));
    }
    for (int i = (n4 << 2) + tid; i < V; i += FNT) lmax = fmaxf(lmax, xrow[i]);
    for (int off = 32; off > 0; off >>= 1) lmax = fmaxf(lmax, __shfl_xor(lmax, off));
    if ((tid & 63) == 0) red[tid >> 6] = lmax;
    __syncthreads();
    if (tid == 0) {
        float r = red[0];
        for (int w = 1; w < FNT / 64; ++w) r = fmaxf(r, red[w]);
        s_m = r / t;
    }
    __syncthreads();
    const float m = s_m;
    float lsum = 0.f;
    for (int i = tid; i < n4; i += FNT) {
        float4 v = x4[i];
        float e0 = expf(v.x / t - m), e1 = expf(v.y / t - m);
        float e2 = expf(v.z / t - m), e3 = expf(v.w / t - m);
        lsum += e0; lsum += e1; lsum += e2; lsum += e3;
        atomicAdd(&hist[__float_as_uint(e0) >> 20], 1u);
        atomicAdd(&hist[__float_as_uint(e1) >> 20], 1u);
        atomicAdd(&hist[__float_as_uint(e2) >> 20], 1u);
        atomicAdd(&hist[__float_as_uint(e3) >> 20], 1u);
    }
    for (int i = (n4 << 2) + tid; i < V; i += FNT) {
        float e = expf(xrow[i] / t - m);
        lsum += e;
        atomicAdd(&hist[__float_as_uint(e) >> 20], 1u);
    }
    for (int off = 32; off > 0; off >>= 1) lsum += __shfl_xor(lsum, off);
    if ((tid & 63) == 0) red[tid >> 6] = lsum;
    __syncthreads();
    if (tid == 0) {
        float r = 0.f;
        for (int w = 0; w < FNT / 64; ++w) r += red[w];
        s_denom = r;
    }
    __syncthreads();
    const float denom = s_denom;
    if (tid < 64) {
        const int lane = tid;
        const int CH = FNBINS / 64;
        const int base = lane * CH;
        unsigned c = 0;
        #pragma unroll
        for (int j = 0; j < CH; ++j) c += hist[base + j];
        unsigned tsuf = c;
        #pragma unroll
        for (int off = 1; off < 64; off <<= 1) {
            unsigned o = __shfl_down(tsuf, off);
            if (lane + off < 64) tsuf += o;
        }
        unsigned long long mask = __ballot(tsuf >= (unsigned)FKMARGIN);
        int lstar = 63 - __builtin_clzll(mask);
        unsigned above = __shfl(tsuf, (lstar + 1) & 63);
        if (lstar == 63) above = 0u;
        if (lane == 0) {
            unsigned run = above;
            int thrbin = lstar * CH;
            for (int bb = lstar * CH + CH - 1; bb >= lstar * CH; --bb) {
                run += hist[bb];
                if (run >= (unsigned)FKMARGIN) { thrbin = bb; break; }
            }
            s_thr = (unsigned)thrbin << 20;
        }
    }
    __syncthreads();
    const unsigned thrkey = s_thr;
    for (int i = tid; i < n4; i += FNT) {
        float4 v = x4[i];
        float e[4] = { expf(v.x / t - m), expf(v.y / t - m),
                       expf(v.z / t - m), expf(v.w / t - m) };
        #pragma unroll
        for (int c = 0; c < 4; ++c) {
            unsigned eb = __float_as_uint(e[c]);
            if (eb >= thrkey) {
                float p = e[c] / denom;
                unsigned pos = atomicAdd(&s_cnt, 1u);
                if (pos < CAND_MAX)
                    cand[pos] = ((u64)__float_as_uint(p) << 32) | (unsigned)(~(unsigned)((i << 2) + c));
            }
        }
    }
    for (int i = (n4 << 2) + tid; i < V; i += FNT) {
        float e = expf(xrow[i] / t - m);
        if (__float_as_uint(e) >= thrkey) {
            float p = e / denom;
            unsigned pos = atomicAdd(&s_cnt, 1u);
            if (pos < CAND_MAX)
                cand[pos] = ((u64)__float_as_uint(p) << 32) | (unsigned)(~(unsigned)i);
        }
    }
    __syncthreads();
    int n = (int)s_cnt; if (n > CAND_MAX) n = CAND_MAX;
    int n2 = 1; while (n2 < n) n2 <<= 1;
    for (int i = n + tid; i < n2; i += FNT) cand[i] = 0ULL;
    __syncthreads();
    for (int k = 2; k <= n2; k <<= 1) {
        for (int j = k >> 1; j > 0; j >>= 1) {
            for (int i = tid; i < n2; i += FNT) {
                int ixj = i ^ j;
                if (ixj > i) {
                    u64 a = cand[i], bb = cand[ixj];
                    bool sw = ((i & k) == 0) ? (a < bb) : (a > bb);
                    if (sw) { cand[i] = bb; cand[ixj] = a; }
                }
            }
            __syncthreads();
        }
    }
    if (tid == 0) {
        const float topp = topps[row], minp = minps[row], uu = us[row];
        int tk = topks[row];
        if (tk > n) tk = n;
        float p0 = __uint_as_float((unsigned)(cand[0] >> 32));
        float thrmp = p0 * minp;
        float cum = 0.f, total = 0.f;
        for (int i = 0; i < tk; ++i) {
            float p = __uint_as_float((unsigned)(cand[i] >> 32));
            cum = cum + p;
            float excl = cum - p;
            float p1 = (excl <= topp) ? p : 0.f;
            float v = (p1 >= thrmp) ? p1 : 0.f;
            total += v;
        }
        float target = uu * total;
        float cdf = 0.f; int sel = -1;
        cum = 0.f;
        for (int i = 0; i < tk; ++i) {
            float p = __uint_as_float((unsigned)(cand[i] >> 32));
            cum = cum + p;
            float excl = cum - p;
            float p1 = (excl <= topp) ? p : 0.f;
            float v = (p1 >= thrmp) ? p1 : 0.f;
            cdf += v;
            if (cdf > target) { sel = i; break; }
        }
        if (sel < 0) sel = 0;
        out[row] = (int)~(unsigned)cand[sel];
    }
}

extern "C" void kernel_launch(void* const* d_in, const int* in_sizes, int n_in,
                              void* d_out, int out_size, void* d_ws, size_t ws_size,
                              hipStream_t stream) {
    const float* logits = (const float*)d_in[0];
    const float* temps  = (const float*)d_in[1];
    const float* minps  = (const float*)d_in[2];
    const float* topps  = (const float*)d_in[3];
    const int*   topks  = (const int*)d_in[4];
    const float* us     = (const float*)d_in[5];
    const int B = in_sizes[1];
    const int V = in_sizes[0] / B;
    int* outp = (int*)d_out;

    const int slen = (((V + S - 1) / S) + 3) & ~3;   // slice length, mult of 4

    size_t need = 0;
    const size_t off_cand = need; need += (size_t)B * CAND_MAX * sizeof(u64);
    const size_t off_cnt  = need; need += (size_t)B * S * sizeof(unsigned);
    const size_t off_max  = need; need += (size_t)B * S * sizeof(float);
    const size_t off_sum  = need; need += (size_t)B * S * sizeof(float);

    if (ws_size < need) {
        sampler_mono<<<dim3(B), dim3(FNT), 0, stream>>>(
            logits, temps, minps, topps, topks, us, outp, V);
        return;
    }

    char* w = (char*)d_ws;
    u64*      gcand  = (u64*)(w + off_cand);
    unsigned* gcnt16 = (unsigned*)(w + off_cnt);
    float*    gmax   = (float*)(w + off_max);
    float*    gsum   = (float*)(w + off_sum);

    // No workspace zeroing needed: every word read is written this call.
    k_pass1<<<dim3(S, B), dim3(NT1), 0, stream>>>(
        logits, temps, gmax, gsum, gcand, gcnt16, V, slen);
    k_finish<<<dim3(B), dim3(NTF), 0, stream>>>(
        logits, gcand, gcnt16, gmax, gsum, temps, minps, topps, topks, us, outp, V);
}